// Round 4
// baseline (103647.339 us; speedup 1.0000x reference)
//
#include <hip/hip_runtime.h>
#include <hip/hip_bf16.h>

// Sizes from the reference
#define T_   4096
#define E_   8

typedef unsigned long long ull;

__device__ __forceinline__ float sigm(float x)  { return 1.0f / (1.0f + __expf(-x)); }
__device__ __forceinline__ float tanh_(float x) { return 1.0f - 2.0f / (__expf(2.0f * x) + 1.0f); }

__device__ __forceinline__ ull aload(const ull* p) {
  return __hip_atomic_load(p, __ATOMIC_RELAXED, __HIP_MEMORY_SCOPE_AGENT);
}
__device__ __forceinline__ ull packvt(float v, int tag) {
  return ((ull)(unsigned)tag << 32) | (ull)__float_as_uint(v);
}

#define FMA_8(ACC, W, VA, VB)                                   \
  ACC[0] = fmaf((W), (VA).x, ACC[0]); ACC[1] = fmaf((W), (VA).y, ACC[1]); \
  ACC[2] = fmaf((W), (VA).z, ACC[2]); ACC[3] = fmaf((W), (VA).w, ACC[3]); \
  ACC[4] = fmaf((W), (VB).x, ACC[4]); ACC[5] = fmaf((W), (VB).y, ACC[5]); \
  ACC[6] = fmaf((W), (VB).z, ACC[6]); ACC[7] = fmaf((W), (VB).w, ACC[7]);

// ---------------------------------------------------------------------------
// initK: K-major packed weight copies + zero the tag arrays.
// wt_p0 PACKED: [k][c] c = wg*64 + r6 (r6 = gate*16+jl, orig col = gate*256+wg*16+jl)
//   k<192 = Wih_p0, else Whh_p0(k-192).  wt_p1 same packing, k<256 ih else hh.
// wt_c0/wt_c1[k][512]; wt_o1[k][512]=Wih_o[:,k] (k<256); wt_o2[k][512]=Wih_o[:,256+k]
// ---------------------------------------------------------------------------
__global__ void initK(const float* __restrict__ Wih_p0, const float* __restrict__ Whh_p0,
                      const float* __restrict__ Wih_p1, const float* __restrict__ Whh_p1,
                      const float* __restrict__ Wih_c0, const float* __restrict__ Whh_c0,
                      const float* __restrict__ Wih_c1, const float* __restrict__ Whh_c1,
                      const float* __restrict__ Wih_o,
                      float* wt_p0, float* wt_p1, float* wt_c0, float* wt_c1,
                      float* wt_o1, float* wt_o2, ull* h0tag, ull* h1tag) {
  const int NW = 458752 + 524288 + 131072 + 131072 + 131072 + 98304;
  const int gsz = gridDim.x * blockDim.x;
  for (int i = blockIdx.x * blockDim.x + threadIdx.x; i < NW; i += gsz) {
    int idx = i;
    if (idx < 458752) { int k = idx >> 10, c = idx & 1023;
      int wg = c >> 6, r6 = c & 63, gate = r6 >> 4, jl = r6 & 15;
      int col = gate * 256 + wg * 16 + jl;
      wt_p0[idx] = (k < 192) ? Wih_p0[col * 192 + k] : Whh_p0[col * 256 + (k - 192)]; continue; }
    idx -= 458752;
    if (idx < 524288) { int k = idx >> 10, c = idx & 1023;
      int wg = c >> 6, r6 = c & 63, gate = r6 >> 4, jl = r6 & 15;
      int col = gate * 256 + wg * 16 + jl;
      wt_p1[idx] = (k < 256) ? Wih_p1[col * 256 + k] : Whh_p1[col * 256 + (k - 256)]; continue; }
    idx -= 524288;
    if (idx < 131072) { int k = idx >> 9, r = idx & 511;
      wt_c0[idx] = (k < 128) ? Wih_c0[r * 128 + k] : Whh_c0[r * 128 + (k - 128)]; continue; }
    idx -= 131072;
    if (idx < 131072) { int k = idx >> 9, r = idx & 511;
      wt_c1[idx] = (k < 128) ? Wih_c1[r * 128 + k] : Whh_c1[r * 128 + (k - 128)]; continue; }
    idx -= 131072;
    if (idx < 131072) { int k = idx >> 9, r = idx & 511;
      wt_o1[idx] = Wih_o[r * 448 + k]; continue; }
    idx -= 131072;
    { int k = idx >> 9, r = idx & 511;
      wt_o2[idx] = Wih_o[r * 448 + 256 + k]; }
  }
  const size_t NT = (size_t)T_ * 2048;
  for (size_t p = (size_t)blockIdx.x * blockDim.x + threadIdx.x; p < NT; p += gsz) {
    h0tag[p] = 0ULL; h1tag[p] = 0ULL;
  }
}

// ---------------------------------------------------------------------------
// opre2K: parallel over t. opre2[t][e][512] = Wih_o[:,256:448] @ x(t,e)  (bf16)
// ---------------------------------------------------------------------------
__global__ void opre2K(const float* __restrict__ feat, const float* __restrict__ wt_o2,
                       __hip_bfloat16* __restrict__ opre2) {
  __shared__ float xb[192 * 8];
  const int t = blockIdx.x, tid = threadIdx.x;
  const float* ft = feat + (size_t)t * 640;
  for (int idx = tid; idx < 192 * 8; idx += 256) {
    int k = idx >> 3, e = idx & 7;
    xb[idx] = (k < 128) ? ft[k] : ft[128 + e * 64 + (k - 128)];
  }
  __syncthreads();
  const int r = tid;
  float A0[8] = {0,0,0,0,0,0,0,0};
  float A1[8] = {0,0,0,0,0,0,0,0};
  const float4* x4 = (const float4*)xb;
  #pragma unroll 2
  for (int k = 0; k < 192; ++k) {
    float w0 = wt_o2[k * 512 + r];
    float w1 = wt_o2[k * 512 + 256 + r];
    float4 a = x4[k * 2], b = x4[k * 2 + 1];
    FMA_8(A0, w0, a, b);
    FMA_8(A1, w1, a, b);
  }
  #pragma unroll
  for (int e = 0; e < 8; ++e) {
    opre2[((size_t)t * 8 + e) * 512 + r]       = __float2bfloat16(A0[e]);
    opre2[((size_t)t * 8 + e) * 512 + 256 + r] = __float2bfloat16(A1[e]);
  }
}

// ---------------------------------------------------------------------------
// phaseA: 32 WGs. WG 0-15 = G1 (layer0), WG 16-31 = G2 (layer1, trailing).
// Weights live in REGISTERS (per-thread K-slice, fully unrolled). h exchange
// uses data-embedded tags: ull = (t+1)<<32 | fp32(h). Consumers poll the data
// directly (prime loads, overlap the h-independent x-part, verify+retry).
// No barriers, no counters, no cache-maintenance ops anywhere.
// ---------------------------------------------------------------------------
__launch_bounds__(256, 1)
__global__ void phaseA(const float* __restrict__ feat,
                       const float* __restrict__ pre_h0, const float* __restrict__ pre_c0,
                       const float* __restrict__ wt_p0, const float* __restrict__ wt_p1,
                       const float* __restrict__ b_p0, const float* __restrict__ b_p1,
                       ull* __restrict__ h0tag, ull* __restrict__ h1tag) {
  __shared__ float lds[6144];
  const int wg = blockIdx.x, tid = threadIdx.x;
  const int r6 = tid & 63, kq = tid >> 6;
  const int uj = tid >> 3, ue = tid & 7;

  if (wg < 16) {
    // ============================ G1: layer0 ============================
    float* xbuf = lds;            // 1536: x(t) [k][e]
    float* hsf  = lds + 1536;     // 2048: h0(t-1) [k][e]
    float* gl   = lds + 3584;     // 2048: partials
    const float* wp = wt_p0 + wg * 64 + r6;
    float wx[48], wh[64];
    #pragma unroll
    for (int i = 0; i < 48; ++i) wx[i] = wp[(size_t)(kq * 48 + i) * 1024];
    #pragma unroll
    for (int i = 0; i < 64; ++i) wh[i] = wp[(size_t)(192 + kq * 64 + i) * 1024];
    const int j = wg * 16 + uj;
    float creg = 0.f, bi = 0.f, bff = 0.f, bg = 0.f, bo = 0.f;
    if (tid < 128) {
      creg = pre_c0[(ue * 2 + 0) * 256 + j];
      bi = b_p0[j]; bff = b_p0[256 + j]; bg = b_p0[512 + j]; bo = b_p0[768 + j];
    }
    for (int idx = tid; idx < 2048; idx += 256) {
      int k = idx >> 3, e = idx & 7;
      hsf[idx] = pre_h0[(e * 2 + 0) * 256 + k];
    }
    for (int idx = tid; idx < 1536; idx += 256) {
      int k = idx >> 3, e = idx & 7;
      xbuf[idx] = (k < 128) ? feat[k] : feat[128 + e * 64 + (k - 128)];
    }
    __syncthreads();
    float Ax[8] = {0,0,0,0,0,0,0,0};
    {
      const float4* x4 = (const float4*)xbuf;
      #pragma unroll
      for (int i = 0; i < 48; ++i) {
        int k = kq * 48 + i;
        float4 a = x4[k * 2], b = x4[k * 2 + 1];
        FMA_8(Ax, wx[i], a, b);
      }
    }
    for (int t = 0; t < T_; ++t) {
      float px[6];
      if (t + 1 < T_) {
        const float* ft1 = feat + (size_t)(t + 1) * 640;
        #pragma unroll
        for (int i = 0; i < 6; ++i) {
          int idx = tid + i * 256; int k = idx >> 3, e = idx & 7;
          px[i] = (k < 128) ? ft1[k] : ft1[128 + e * 64 + (k - 128)];
        }
      }
      float A[8];
      #pragma unroll
      for (int i = 0; i < 8; ++i) A[i] = Ax[i];
      {
        const float4* h4 = (const float4*)hsf;
        #pragma unroll
        for (int i = 0; i < 64; ++i) {
          int kk = kq * 64 + i;
          float4 a = h4[kk * 2], b = h4[kk * 2 + 1];
          FMA_8(A, wh[i], a, b);
        }
      }
      {
        float4* g4 = (float4*)gl;
        g4[(kq * 64 + r6) * 2]     = make_float4(A[0], A[1], A[2], A[3]);
        g4[(kq * 64 + r6) * 2 + 1] = make_float4(A[4], A[5], A[6], A[7]);
      }
      __syncthreads();                             // S1: gl ready; hsf/xbuf consumed
      if (tid < 128) {
        float s0 = 0.f, s1 = 0.f, s2 = 0.f, s3 = 0.f;
        #pragma unroll
        for (int q = 0; q < 4; ++q) {
          s0 += gl[q * 512 + tid];       s1 += gl[q * 512 + 128 + tid];
          s2 += gl[q * 512 + 256 + tid]; s3 += gl[q * 512 + 384 + tid];
        }
        float c2 = sigm(s1 + bff) * creg + sigm(s0 + bi) * tanh_(s2 + bg);
        float h2 = sigm(s3 + bo) * tanh_(c2);
        creg = c2;
        __hip_atomic_store(&h0tag[(size_t)t * 2048 + wg * 128 + tid],
                           packvt(h2, t + 1), __ATOMIC_RELAXED, __HIP_MEMORY_SCOPE_AGENT);
      }
      if (t + 1 >= T_) break;
      ull v[8];
      const ull* gb = h0tag + (size_t)t * 2048;
      #pragma unroll
      for (int i = 0; i < 8; ++i) v[i] = aload(gb + tid + i * 256);   // prime
      #pragma unroll
      for (int i = 0; i < 6; ++i) xbuf[tid + i * 256] = px[i];
      __syncthreads();                             // S2: xbuf=x(t+1); gl consumed
      #pragma unroll
      for (int i = 0; i < 8; ++i) Ax[i] = 0.f;
      {
        const float4* x4 = (const float4*)xbuf;
        #pragma unroll
        for (int i = 0; i < 48; ++i) {
          int k = kq * 48 + i;
          float4 a = x4[k * 2], b = x4[k * 2 + 1];
          FMA_8(Ax, wx[i], a, b);
        }
      }
      const int want = t + 1;
      bool all;
      do {
        all = true;
        #pragma unroll
        for (int i = 0; i < 8; ++i)
          if ((int)(v[i] >> 32) != want) {
            v[i] = aload(gb + tid + i * 256);
            if ((int)(v[i] >> 32) != want) all = false;
          }
      } while (!all);
      #pragma unroll
      for (int i = 0; i < 8; ++i) hsf[tid + i * 256] = __uint_as_float((unsigned)v[i]);
      __syncthreads();                             // S3: hsf = h0(t)
    }
  } else {
    // ============================ G2: layer1 ============================
    const int wgl = wg - 16;
    float* xh0 = lds;             // 2048: h0(t) [k][e]
    float* hsf = lds + 2048;      // 2048: h1(t-1) [k][e]
    float* gl  = lds + 4096;      // 2048
    const float* wp = wt_p1 + wgl * 64 + r6;
    float wx[64], wh[64];
    #pragma unroll
    for (int i = 0; i < 64; ++i) wx[i] = wp[(size_t)(kq * 64 + i) * 1024];
    #pragma unroll
    for (int i = 0; i < 64; ++i) wh[i] = wp[(size_t)(256 + kq * 64 + i) * 1024];
    const int j = wgl * 16 + uj;
    float creg = 0.f, bi = 0.f, bff = 0.f, bg = 0.f, bo = 0.f;
    if (tid < 128) {
      creg = pre_c0[(ue * 2 + 1) * 256 + j];
      bi = b_p1[j]; bff = b_p1[256 + j]; bg = b_p1[512 + j]; bo = b_p1[768 + j];
    }
    for (int idx = tid; idx < 2048; idx += 256) {
      int k = idx >> 3, e = idx & 7;
      hsf[idx] = pre_h0[(e * 2 + 1) * 256 + k];
    }
    __syncthreads();
    {   // gather h0(0), want = 1
      ull v[8];
      #pragma unroll
      for (int i = 0; i < 8; ++i) v[i] = aload(h0tag + tid + i * 256);
      bool all;
      do {
        all = true;
        #pragma unroll
        for (int i = 0; i < 8; ++i)
          if ((int)(v[i] >> 32) != 1) {
            v[i] = aload(h0tag + tid + i * 256);
            if ((int)(v[i] >> 32) != 1) all = false;
          }
      } while (!all);
      #pragma unroll
      for (int i = 0; i < 8; ++i) xh0[tid + i * 256] = __uint_as_float((unsigned)v[i]);
    }
    __syncthreads();
    float Ax[8] = {0,0,0,0,0,0,0,0};
    {
      const float4* x4 = (const float4*)xh0;
      #pragma unroll
      for (int i = 0; i < 64; ++i) {
        int kk = kq * 64 + i;
        float4 a = x4[kk * 2], b = x4[kk * 2 + 1];
        FMA_8(Ax, wx[i], a, b);
      }
    }
    for (int t = 0; t < T_; ++t) {
      float A[8];
      #pragma unroll
      for (int i = 0; i < 8; ++i) A[i] = Ax[i];
      {
        const float4* h4 = (const float4*)hsf;
        #pragma unroll
        for (int i = 0; i < 64; ++i) {
          int kk = kq * 64 + i;
          float4 a = h4[kk * 2], b = h4[kk * 2 + 1];
          FMA_8(A, wh[i], a, b);
        }
      }
      {
        float4* g4 = (float4*)gl;
        g4[(kq * 64 + r6) * 2]     = make_float4(A[0], A[1], A[2], A[3]);
        g4[(kq * 64 + r6) * 2 + 1] = make_float4(A[4], A[5], A[6], A[7]);
      }
      __syncthreads();                             // S1
      if (tid < 128) {
        float s0 = 0.f, s1 = 0.f, s2 = 0.f, s3 = 0.f;
        #pragma unroll
        for (int q = 0; q < 4; ++q) {
          s0 += gl[q * 512 + tid];       s1 += gl[q * 512 + 128 + tid];
          s2 += gl[q * 512 + 256 + tid]; s3 += gl[q * 512 + 384 + tid];
        }
        float c2 = sigm(s1 + bff) * creg + sigm(s0 + bi) * tanh_(s2 + bg);
        float h2 = sigm(s3 + bo) * tanh_(c2);
        creg = c2;
        __hip_atomic_store(&h1tag[(size_t)t * 2048 + wgl * 128 + tid],
                           packvt(h2, t + 1), __ATOMIC_RELAXED, __HIP_MEMORY_SCOPE_AGENT);
      }
      if (t + 1 >= T_) break;
      ull vh[8];
      const ull* hb = h1tag + (size_t)t * 2048;
      #pragma unroll
      for (int i = 0; i < 8; ++i) vh[i] = aload(hb + tid + i * 256);  // prime h1(t)
      // poll-gather h0(t+1), want = t+2 (G1 runs ahead; usually ready)
      ull v0[8];
      const ull* gb = h0tag + (size_t)(t + 1) * 2048;
      #pragma unroll
      for (int i = 0; i < 8; ++i) v0[i] = aload(gb + tid + i * 256);
      {
        const int want0 = t + 2;
        bool all;
        do {
          all = true;
          #pragma unroll
          for (int i = 0; i < 8; ++i)
            if ((int)(v0[i] >> 32) != want0) {
              v0[i] = aload(gb + tid + i * 256);
              if ((int)(v0[i] >> 32) != want0) all = false;
            }
        } while (!all);
      }
      __syncthreads();                             // S2: gl consumed; xh0 reads done
      #pragma unroll
      for (int i = 0; i < 8; ++i) xh0[tid + i * 256] = __uint_as_float((unsigned)v0[i]);
      __syncthreads();                             // S3: xh0 = h0(t+1)
      #pragma unroll
      for (int i = 0; i < 8; ++i) Ax[i] = 0.f;
      {
        const float4* x4 = (const float4*)xh0;
        #pragma unroll
        for (int i = 0; i < 64; ++i) {
          int kk = kq * 64 + i;
          float4 a = x4[kk * 2], b = x4[kk * 2 + 1];
          FMA_8(Ax, wx[i], a, b);
        }
      }
      {
        const int want = t + 1;
        bool all;
        do {
          all = true;
          #pragma unroll
          for (int i = 0; i < 8; ++i)
            if ((int)(vh[i] >> 32) != want) {
              vh[i] = aload(hb + tid + i * 256);
              if ((int)(vh[i] >> 32) != want) all = false;
            }
        } while (!all);
      }
      #pragma unroll
      for (int i = 0; i < 8; ++i) hsf[tid + i * 256] = __uint_as_float((unsigned)vh[i]);
      __syncthreads();                             // S4: hsf = h1(t)
    }
  }
}

// ---------------------------------------------------------------------------
// fcK: parallel over t. pre_out[t][e][c] = leaky(Wfc @ h1(t) + bfc)
// h1tag layout: [t][j*8+e], fp32 value in low 32 bits.
// ---------------------------------------------------------------------------
__global__ void fcK(const ull* __restrict__ h1tag, const float* __restrict__ Wfc,
                    const float* __restrict__ bfc, float* __restrict__ pre_out) {
  __shared__ float hl[2048];
  const int t = blockIdx.x, tid = threadIdx.x;
  for (int idx = tid; idx < 2048; idx += 256)
    hl[idx] = __uint_as_float((unsigned)h1tag[(size_t)t * 2048 + idx]);
  __syncthreads();
  const int c = tid >> 1, half = tid & 1;
  float b = bfc[c];
  float acc[4] = {b, b, b, b};
  const float4* h4 = (const float4*)hl;
  const float* wrow = Wfc + c * 256;
  #pragma unroll 4
  for (int k = 0; k < 256; ++k) {
    float w = wrow[k];
    float4 x = h4[k * 2 + half];
    acc[0] = fmaf(w, x.x, acc[0]); acc[1] = fmaf(w, x.y, acc[1]);
    acc[2] = fmaf(w, x.z, acc[2]); acc[3] = fmaf(w, x.w, acc[3]);
  }
  #pragma unroll
  for (int i = 0; i < 4; ++i) {
    int e = half * 4 + i;
    float v = acc[i];
    v = (v > 0.f) ? v : 0.05f * v;
    pre_out[((size_t)t * 8 + e) * 128 + c] = v;
  }
}

// ---------------------------------------------------------------------------
// comm cell for phase B
// ---------------------------------------------------------------------------
__device__ __forceinline__ void comm_cell(
    const float* __restrict__ wt, const float* __restrict__ bias,
    const float* xin, float* hL, float* cL, float* glb, float* hout,
    float alpha, int tid) {
  const int r = tid;
  float A0[8] = {0,0,0,0,0,0,0,0};
  float A1[8] = {0,0,0,0,0,0,0,0};
  const float4* x4 = (const float4*)xin;
  #pragma unroll 2
  for (int k = 0; k < 128; ++k) {
    float w0 = wt[k * 512 + r];
    float w1 = wt[k * 512 + 256 + r];
    float4 a = x4[k * 2], b = x4[k * 2 + 1];
    FMA_8(A0, w0, a, b);
    FMA_8(A1, w1, a, b);
  }
  const float4* h4 = (const float4*)hL;
  #pragma unroll 2
  for (int k = 0; k < 128; ++k) {
    float w0 = wt[(128 + k) * 512 + r];
    float w1 = wt[(128 + k) * 512 + 256 + r];
    float4 a = h4[k * 2], b = h4[k * 2 + 1];
    FMA_8(A0, w0, a, b);
    FMA_8(A1, w1, a, b);
  }
  #pragma unroll
  for (int tt = 0; tt < 8; ++tt) { glb[r * 8 + tt] = A0[tt]; glb[(256 + r) * 8 + tt] = A1[tt]; }
  __syncthreads();
  for (int idx = tid; idx < 1024; idx += 256) {
    int jj = idx >> 3, tt = idx & 7;
    float gi = glb[jj * 8 + tt]         + bias[jj];
    float gf = glb[(128 + jj) * 8 + tt] + bias[128 + jj];
    float gg = glb[(256 + jj) * 8 + tt] + bias[256 + jj];
    float go = glb[(384 + jj) * 8 + tt] + bias[384 + jj];
    float cold = cL[idx], hold = hL[idx];
    float c2 = sigm(gf) * cold + sigm(gi) * tanh_(gg);
    float h2 = sigm(go) * tanh_(c2);
    float hb = fmaf(alpha, h2 - hold, hold);
    float cb = fmaf(alpha, c2 - cold, cold);
    hL[idx] = hb; cL[idx] = cb;
    if (hout) hout[idx] = hb;
  }
  __syncthreads();
}

// ---------------------------------------------------------------------------
// phaseB: parallel over t (8 timesteps / WG); emits opre1 (incl. b_o)
// ---------------------------------------------------------------------------
__launch_bounds__(256, 2)
__global__ void phaseB(const float* __restrict__ pre_out,
                       const float* __restrict__ wt_c0, const float* __restrict__ wt_c1,
                       const float* __restrict__ b_c0, const float* __restrict__ b_c1,
                       const float* __restrict__ wt_o1, const float* __restrict__ b_o,
                       float* __restrict__ opre1) {
  __shared__ float pol[128 * 8];
  __shared__ float ch0[128 * 8], cc0[128 * 8], ch1[128 * 8], cc1[128 * 8];
  __shared__ float h0b[128 * 8];
  __shared__ float glb[512 * 8];
  const int wg = blockIdx.x, tid = threadIdx.x;
  const int t0 = wg * 8;
  for (int idx = tid; idx < 1024; idx += 256) { ch0[idx]=0.f; cc0[idx]=0.f; ch1[idx]=0.f; cc1[idx]=0.f; }
  __syncthreads();
  float alpha = 1.0f;
  for (int rd = 0; rd < 3; ++rd) {
    for (int e = 0; e < E_; ++e) {
      for (int idx = tid; idx < 1024; idx += 256) {
        int tt = idx >> 7, k = idx & 127;
        pol[k * 8 + tt] = pre_out[(((size_t)(t0 + tt)) * 8 + e) * 128 + k];
      }
      __syncthreads();
      comm_cell(wt_c0, b_c0, pol, ch0, cc0, glb, h0b, alpha, tid);
      comm_cell(wt_c1, b_c1, h0b, ch1, cc1, glb, nullptr, alpha, tid);
    }
    alpha *= 0.333f;
  }
  {
    const int r = tid;
    float A0[8], A1[8];
    #pragma unroll
    for (int tt = 0; tt < 8; ++tt) { A0[tt] = b_o[r]; A1[tt] = b_o[256 + r]; }
    const float4* c04 = (const float4*)cc0;
    const float4* c14 = (const float4*)cc1;
    #pragma unroll 2
    for (int k = 0; k < 128; ++k) {
      float w0 = wt_o1[k * 512 + r], w1 = wt_o1[k * 512 + 256 + r];
      float4 a = c04[k * 2], b = c04[k * 2 + 1];
      FMA_8(A0, w0, a, b);
      FMA_8(A1, w1, a, b);
    }
    #pragma unroll 2
    for (int k = 0; k < 128; ++k) {
      float w0 = wt_o1[(128 + k) * 512 + r], w1 = wt_o1[(128 + k) * 512 + 256 + r];
      float4 a = c14[k * 2], b = c14[k * 2 + 1];
      FMA_8(A0, w0, a, b);
      FMA_8(A1, w1, a, b);
    }
    #pragma unroll
    for (int tt = 0; tt < 8; ++tt) {
      opre1[((size_t)(t0 + tt)) * 512 + r]       = A0[tt];
      opre1[((size_t)(t0 + tt)) * 512 + 256 + r] = A1[tt];
    }
  }
}

// ---------------------------------------------------------------------------
// phaseC: 8 WGs, one per ensemble e. No inter-WG sync; Whh_o in registers.
// ---------------------------------------------------------------------------
__launch_bounds__(256, 1)
__global__ void phaseC(const float* __restrict__ opre1, const __hip_bfloat16* __restrict__ opre2,
                       const float* __restrict__ Whh_o, const float* __restrict__ out_h0,
                       const float* __restrict__ out_c0, float* __restrict__ oh_g) {
  __shared__ float ohl[128];
  __shared__ float gl[512];
  const int e = blockIdx.x, tid = threadIdx.x;
  const int r0 = tid, r1 = tid + 256;
  float w0[128], w1[128];
  #pragma unroll
  for (int k = 0; k < 128; ++k) w0[k] = Whh_o[r0 * 128 + k];
  #pragma unroll
  for (int k = 0; k < 128; ++k) w1[k] = Whh_o[r1 * 128 + k];
  if (tid < 128) ohl[tid] = out_h0[e * 128 + tid];
  float creg = (tid < 128) ? out_c0[e * 128 + tid] : 0.f;
  __syncthreads();
  float p0a = opre1[r0], p0b = opre1[r1];
  float q0a = __bfloat162float(opre2[(size_t)e * 512 + r0]);
  float q0b = __bfloat162float(opre2[(size_t)e * 512 + r1]);
  for (int t = 0; t < T_; ++t) {
    float a0 = p0a + q0a, a1 = p0b + q0b;
    if (t + 1 < T_) {
      p0a = opre1[(size_t)(t + 1) * 512 + r0];
      p0b = opre1[(size_t)(t + 1) * 512 + r1];
      q0a = __bfloat162float(opre2[((size_t)(t + 1) * 8 + e) * 512 + r0]);
      q0b = __bfloat162float(opre2[((size_t)(t + 1) * 8 + e) * 512 + r1]);
    }
    const float4* o4 = (const float4*)ohl;
    #pragma unroll
    for (int kk = 0; kk < 32; ++kk) {
      float4 x = o4[kk];
      a0 = fmaf(w0[kk * 4 + 0], x.x, a0); a0 = fmaf(w0[kk * 4 + 1], x.y, a0);
      a0 = fmaf(w0[kk * 4 + 2], x.z, a0); a0 = fmaf(w0[kk * 4 + 3], x.w, a0);
      a1 = fmaf(w1[kk * 4 + 0], x.x, a1); a1 = fmaf(w1[kk * 4 + 1], x.y, a1);
      a1 = fmaf(w1[kk * 4 + 2], x.z, a1); a1 = fmaf(w1[kk * 4 + 3], x.w, a1);
    }
    gl[r0] = a0; gl[r1] = a1;
    __syncthreads();
    if (tid < 128) {
      float gi = gl[tid], gf = gl[128 + tid], gg = gl[256 + tid], go = gl[384 + tid];
      float c2 = sigm(gf) * creg + sigm(gi) * tanh_(gg);
      float h2 = sigm(go) * tanh_(c2);
      creg = c2;
      ohl[tid] = h2;
      oh_g[(size_t)t * 1024 + e * 128 + tid] = h2;
    }
    __syncthreads();
  }
}

// ---------------------------------------------------------------------------
// phaseD: parallel over t: softmaxes
// ---------------------------------------------------------------------------
__global__ void phaseD(const float* __restrict__ oh_g,
                       const float* __restrict__ Wtar, const float* __restrict__ btar,
                       const float* __restrict__ Wdir, const float* __restrict__ bdir,
                       float* __restrict__ outp) {
  __shared__ float ohl[1024];
  const int t = blockIdx.x, tid = threadIdx.x;  // 64 threads
  for (int idx = tid; idx < 1024; idx += 64) ohl[idx] = oh_g[(size_t)t * 1024 + idx];
  __syncthreads();
  const int f = tid;
  for (int e = 0; e < E_; ++e) {
    float acc = btar[f];
    const float* wr = Wtar + f * 128;
    #pragma unroll 4
    for (int k = 0; k < 128; ++k) acc = fmaf(wr[k], ohl[e * 128 + k], acc);
    float m = acc;
    #pragma unroll
    for (int off = 32; off; off >>= 1) m = fmaxf(m, __shfl_xor(m, off, 64));
    float ex = __expf(acc - m);
    float s = ex;
    #pragma unroll
    for (int off = 32; off; off >>= 1) s += __shfl_xor(s, off, 64);
    outp[((size_t)t * 8 + e) * 64 + f] = ex / s;
  }
  if (tid < 8) {
    int e = tid;
    float d0 = bdir[0], d1 = bdir[1], d2 = bdir[2];
    #pragma unroll 4
    for (int k = 0; k < 128; ++k) {
      float x = ohl[e * 128 + k];
      d0 = fmaf(Wdir[k], x, d0);
      d1 = fmaf(Wdir[128 + k], x, d1);
      d2 = fmaf(Wdir[256 + k], x, d2);
    }
    float m = fmaxf(d0, fmaxf(d1, d2));
    float x0 = __expf(d0 - m), x1 = __expf(d1 - m), x2 = __expf(d2 - m);
    float s = x0 + x1 + x2;
    float* dp = outp + (size_t)T_ * 8 * 64 + ((size_t)t * 8 + e) * 3;
    dp[0] = x0 / s; dp[1] = x1 / s; dp[2] = x2 / s;
  }
}

extern "C" void kernel_launch(void* const* d_in, const int* in_sizes, int n_in,
                              void* d_out, int out_size, void* d_ws, size_t ws_size,
                              hipStream_t stream) {
  (void)in_sizes; (void)n_in; (void)out_size; (void)ws_size;
  const float* feat   = (const float*)d_in[0];
  const float* pre_h0 = (const float*)d_in[1];
  const float* pre_c0 = (const float*)d_in[2];
  const float* out_h0 = (const float*)d_in[3];
  const float* out_c0 = (const float*)d_in[4];
  const float* Wih_p0 = (const float*)d_in[5];
  const float* Whh_p0 = (const float*)d_in[6];
  const float* b_p0   = (const float*)d_in[7];
  const float* Wih_p1 = (const float*)d_in[8];
  const float* Whh_p1 = (const float*)d_in[9];
  const float* b_p1   = (const float*)d_in[10];
  const float* Wfc    = (const float*)d_in[11];
  const float* bfc    = (const float*)d_in[12];
  const float* Wih_c0 = (const float*)d_in[13];
  const float* Whh_c0 = (const float*)d_in[14];
  const float* b_c0   = (const float*)d_in[15];
  const float* Wih_c1 = (const float*)d_in[16];
  const float* Whh_c1 = (const float*)d_in[17];
  const float* b_c1   = (const float*)d_in[18];
  const float* Wih_o  = (const float*)d_in[19];
  const float* Whh_o  = (const float*)d_in[20];
  const float* b_o    = (const float*)d_in[21];
  const float* Wtar   = (const float*)d_in[22];
  const float* btar   = (const float*)d_in[23];
  const float* Wdir   = (const float*)d_in[24];
  const float* bdir   = (const float*)d_in[25];
  float* outp = (float*)d_out;

  float* ws = (float*)d_ws;
  size_t off = 0;
  float* pre_outB = ws + off; off += (size_t)T_ * E_ * 128;
  float* opre1    = ws + off; off += (size_t)T_ * 512;
  float* oh_g     = ws + off; off += (size_t)T_ * E_ * 128;
  float* wt_p0    = ws + off; off += (size_t)448 * 1024;
  float* wt_p1    = ws + off; off += (size_t)512 * 1024;
  float* wt_c0    = ws + off; off += (size_t)256 * 512;
  float* wt_c1    = ws + off; off += (size_t)256 * 512;
  float* wt_o1    = ws + off; off += (size_t)256 * 512;
  float* wt_o2    = ws + off; off += (size_t)192 * 512;
  __hip_bfloat16* opre2 = (__hip_bfloat16*)(ws + off);
  off += (size_t)T_ * E_ * 512 / 2;
  ull* h0tag = (ull*)(ws + off); off += (size_t)T_ * 2048 * 2;
  ull* h1tag = (ull*)(ws + off); off += (size_t)T_ * 2048 * 2;

  initK<<<dim3(1024), dim3(256), 0, stream>>>(
      Wih_p0, Whh_p0, Wih_p1, Whh_p1, Wih_c0, Whh_c0, Wih_c1, Whh_c1, Wih_o,
      wt_p0, wt_p1, wt_c0, wt_c1, wt_o1, wt_o2, h0tag, h1tag);
  opre2K<<<dim3(T_), dim3(256), 0, stream>>>(feat, wt_o2, opre2);
  phaseA<<<dim3(32), dim3(256), 0, stream>>>(
      feat, pre_h0, pre_c0, wt_p0, wt_p1, b_p0, b_p1, h0tag, h1tag);
  fcK<<<dim3(T_), dim3(256), 0, stream>>>(h1tag, Wfc, bfc, pre_outB);
  phaseB<<<dim3(T_ / 8), dim3(256), 0, stream>>>(
      pre_outB, wt_c0, wt_c1, b_c0, b_c1, wt_o1, b_o, opre1);
  phaseC<<<dim3(E_), dim3(256), 0, stream>>>(
      opre1, opre2, Whh_o, out_h0, out_c0, oh_g);
  phaseD<<<dim3(T_), dim3(64), 0, stream>>>(oh_g, Wtar, btar, Wdir, bdir, outp);
}

// Round 5
// 101072.083 us; speedup vs baseline: 1.0255x; 1.0255x over previous
//
#include <hip/hip_runtime.h>
#include <hip/hip_bf16.h>

// Sizes from the reference
#define T_   4096
#define E_   8

typedef unsigned long long ull;

__device__ __forceinline__ float sigm(float x)  { return 1.0f / (1.0f + __expf(-x)); }
__device__ __forceinline__ float tanh_(float x) { return 1.0f - 2.0f / (__expf(2.0f * x) + 1.0f); }

__device__ __forceinline__ ull aload64(const ull* p) {
  return __hip_atomic_load(p, __ATOMIC_RELAXED, __HIP_MEMORY_SCOPE_AGENT);
}
__device__ __forceinline__ int aload32(const int* p) {
  return __hip_atomic_load(p, __ATOMIC_RELAXED, __HIP_MEMORY_SCOPE_AGENT);
}

#define FMA_8(ACC, W, VA, VB)                                   \
  ACC[0] = fmaf((W), (VA).x, ACC[0]); ACC[1] = fmaf((W), (VA).y, ACC[1]); \
  ACC[2] = fmaf((W), (VA).z, ACC[2]); ACC[3] = fmaf((W), (VA).w, ACC[3]); \
  ACC[4] = fmaf((W), (VB).x, ACC[4]); ACC[5] = fmaf((W), (VB).y, ACC[5]); \
  ACC[6] = fmaf((W), (VB).z, ACC[6]); ACC[7] = fmaf((W), (VB).w, ACC[7]);

// ---------------------------------------------------------------------------
// initK: K-major packed weight copies + zero flag arrays.
// wt_p0 PACKED: [k][c] c = wg*64 + r6 (r6 = gate*16+jl, orig col = gate*256+wg*16+jl)
//   k<192 = Wih_p0, else Whh_p0(k-192).  wt_p1 same packing, k<256 ih else hh.
// wt_c0/wt_c1[k][512]; wt_o1[k][512]=Wih_o[:,k] (k<256); wt_o2[k][512]=Wih_o[:,256+k]
// flagsA/flagsB: one 128-B line per (t, wg): index (t*16+wg)*32.
// ---------------------------------------------------------------------------
__global__ void initK(const float* __restrict__ Wih_p0, const float* __restrict__ Whh_p0,
                      const float* __restrict__ Wih_p1, const float* __restrict__ Whh_p1,
                      const float* __restrict__ Wih_c0, const float* __restrict__ Whh_c0,
                      const float* __restrict__ Wih_c1, const float* __restrict__ Whh_c1,
                      const float* __restrict__ Wih_o,
                      float* wt_p0, float* wt_p1, float* wt_c0, float* wt_c1,
                      float* wt_o1, float* wt_o2, int* flags) {
  const int NW = 458752 + 524288 + 131072 + 131072 + 131072 + 98304;
  const int NF = 2 * T_ * 16 * 32;
  const int NTOT = NW + NF;
  const int gsz = gridDim.x * blockDim.x;
  for (int i = blockIdx.x * blockDim.x + threadIdx.x; i < NTOT; i += gsz) {
    int idx = i;
    if (idx < 458752) { int k = idx >> 10, c = idx & 1023;
      int wg = c >> 6, r6 = c & 63, gate = r6 >> 4, jl = r6 & 15;
      int col = gate * 256 + wg * 16 + jl;
      wt_p0[idx] = (k < 192) ? Wih_p0[col * 192 + k] : Whh_p0[col * 256 + (k - 192)]; continue; }
    idx -= 458752;
    if (idx < 524288) { int k = idx >> 10, c = idx & 1023;
      int wg = c >> 6, r6 = c & 63, gate = r6 >> 4, jl = r6 & 15;
      int col = gate * 256 + wg * 16 + jl;
      wt_p1[idx] = (k < 256) ? Wih_p1[col * 256 + k] : Whh_p1[col * 256 + (k - 256)]; continue; }
    idx -= 524288;
    if (idx < 131072) { int k = idx >> 9, r = idx & 511;
      wt_c0[idx] = (k < 128) ? Wih_c0[r * 128 + k] : Whh_c0[r * 128 + (k - 128)]; continue; }
    idx -= 131072;
    if (idx < 131072) { int k = idx >> 9, r = idx & 511;
      wt_c1[idx] = (k < 128) ? Wih_c1[r * 128 + k] : Whh_c1[r * 128 + (k - 128)]; continue; }
    idx -= 131072;
    if (idx < 131072) { int k = idx >> 9, r = idx & 511;
      wt_o1[idx] = Wih_o[r * 448 + k]; continue; }
    idx -= 131072;
    if (idx < 98304) { int k = idx >> 9, r = idx & 511;
      wt_o2[idx] = Wih_o[r * 448 + 256 + k]; continue; }
    idx -= 98304;
    flags[idx] = 0;
  }
}

// ---------------------------------------------------------------------------
// opre2K: parallel over t. opre2[t][e][512] = Wih_o[:,256:448] @ x(t,e)  (bf16)
// ---------------------------------------------------------------------------
__global__ void opre2K(const float* __restrict__ feat, const float* __restrict__ wt_o2,
                       __hip_bfloat16* __restrict__ opre2) {
  __shared__ float xb[192 * 8];
  const int t = blockIdx.x, tid = threadIdx.x;
  const float* ft = feat + (size_t)t * 640;
  for (int idx = tid; idx < 192 * 8; idx += 256) {
    int k = idx >> 3, e = idx & 7;
    xb[idx] = (k < 128) ? ft[k] : ft[128 + e * 64 + (k - 128)];
  }
  __syncthreads();
  const int r = tid;
  float A0[8] = {0,0,0,0,0,0,0,0};
  float A1[8] = {0,0,0,0,0,0,0,0};
  const float4* x4 = (const float4*)xb;
  #pragma unroll 2
  for (int k = 0; k < 192; ++k) {
    float w0 = wt_o2[k * 512 + r];
    float w1 = wt_o2[k * 512 + 256 + r];
    float4 a = x4[k * 2], b = x4[k * 2 + 1];
    FMA_8(A0, w0, a, b);
    FMA_8(A1, w1, a, b);
  }
  #pragma unroll
  for (int e = 0; e < 8; ++e) {
    opre2[((size_t)t * 8 + e) * 512 + r]       = __float2bfloat16(A0[e]);
    opre2[((size_t)t * 8 + e) * 512 + 256 + r] = __float2bfloat16(A1[e]);
  }
}

// ---------------------------------------------------------------------------
// phaseA: 32 WGs. WG 0-15 = G1 (layer0), WG 16-31 = G2 (layer1, trailing).
// Weights in REGISTERS. Exchange: relaxed agent stores into fp32 T-arrays,
// drained by __syncthreads (vmcnt0 before s_barrier); then one flag store per
// WG per step on its OWN 128-B line; detect = 16 lanes polling 16 independent
// lines in parallel (one fabric RTT, no RMW serialization). The h-independent
// part of step t+1 is computed between flag-store and poll to hide latency.
// ---------------------------------------------------------------------------
__launch_bounds__(256, 1)
__global__ void phaseA(const float* __restrict__ feat,
                       const float* __restrict__ pre_h0, const float* __restrict__ pre_c0,
                       const float* __restrict__ wt_p0, const float* __restrict__ wt_p1,
                       const float* __restrict__ b_p0, const float* __restrict__ b_p1,
                       float* __restrict__ h0all, float* __restrict__ h1all,
                       int* __restrict__ flagsA, int* __restrict__ flagsB) {
  __shared__ float lds[6144];
  const int wg = blockIdx.x, tid = threadIdx.x;
  const int r6 = tid & 63, kq = tid >> 6;
  const int uj = tid >> 3, ue = tid & 7;

  if (wg < 16) {
    // ============================ G1: layer0 ============================
    float* xbuf = lds;            // 1536: x(t) [k][e]
    float* hsf  = lds + 1536;     // 2048: h0(t-1) [k][e]
    float* gl   = lds + 3584;     // 2048: partials
    const float* wp = wt_p0 + wg * 64 + r6;
    float wx[48], wh[64];
    #pragma unroll
    for (int i = 0; i < 48; ++i) wx[i] = wp[(size_t)(kq * 48 + i) * 1024];
    #pragma unroll
    for (int i = 0; i < 64; ++i) wh[i] = wp[(size_t)(192 + kq * 64 + i) * 1024];
    const int j = wg * 16 + uj;
    float creg = 0.f, bi = 0.f, bff = 0.f, bg = 0.f, bo = 0.f;
    if (tid < 128) {
      creg = pre_c0[(ue * 2 + 0) * 256 + j];
      bi = b_p0[j]; bff = b_p0[256 + j]; bg = b_p0[512 + j]; bo = b_p0[768 + j];
    }
    for (int idx = tid; idx < 2048; idx += 256) {
      int k = idx >> 3, e = idx & 7;
      hsf[idx] = pre_h0[(e * 2 + 0) * 256 + k];
    }
    for (int idx = tid; idx < 1536; idx += 256) {
      int k = idx >> 3, e = idx & 7;
      xbuf[idx] = (k < 128) ? feat[k] : feat[128 + e * 64 + (k - 128)];
    }
    __syncthreads();
    float Ax[8] = {0,0,0,0,0,0,0,0};
    {
      const float4* x4 = (const float4*)xbuf;
      #pragma unroll
      for (int i = 0; i < 48; ++i) {
        int k = kq * 48 + i;
        float4 a = x4[k * 2], b = x4[k * 2 + 1];
        FMA_8(Ax, wx[i], a, b);
      }
    }
    for (int t = 0; t < T_; ++t) {
      float px[6];
      if (t + 1 < T_) {
        const float* ft1 = feat + (size_t)(t + 1) * 640;
        #pragma unroll
        for (int i = 0; i < 6; ++i) {
          int idx = tid + i * 256; int k = idx >> 3, e = idx & 7;
          px[i] = (k < 128) ? ft1[k] : ft1[128 + e * 64 + (k - 128)];
        }
      }
      float A[8];
      #pragma unroll
      for (int i = 0; i < 8; ++i) A[i] = Ax[i];
      {
        const float4* h4 = (const float4*)hsf;
        #pragma unroll
        for (int i = 0; i < 64; ++i) {
          int kk = kq * 64 + i;
          float4 a = h4[kk * 2], b = h4[kk * 2 + 1];
          FMA_8(A, wh[i], a, b);
        }
      }
      {
        float4* g4 = (float4*)gl;
        g4[(kq * 64 + r6) * 2]     = make_float4(A[0], A[1], A[2], A[3]);
        g4[(kq * 64 + r6) * 2 + 1] = make_float4(A[4], A[5], A[6], A[7]);
      }
      __syncthreads();                             // S1: gl ready
      if (tid < 128) {
        float s0 = 0.f, s1 = 0.f, s2 = 0.f, s3 = 0.f;
        #pragma unroll
        for (int q = 0; q < 4; ++q) {
          s0 += gl[q * 512 + tid];       s1 += gl[q * 512 + 128 + tid];
          s2 += gl[q * 512 + 256 + tid]; s3 += gl[q * 512 + 384 + tid];
        }
        float c2 = sigm(s1 + bff) * creg + sigm(s0 + bi) * tanh_(s2 + bg);
        float h2 = sigm(s3 + bo) * tanh_(c2);
        creg = c2;
        __hip_atomic_store(&h0all[(size_t)t * 2048 + wg * 128 + tid], h2,
                           __ATOMIC_RELAXED, __HIP_MEMORY_SCOPE_AGENT);
      }
      __syncthreads();                             // S2: publish drained (vmcnt0)
      if (tid == 0)
        __hip_atomic_store(&flagsA[((size_t)t * 16 + wg) * 32], 1,
                           __ATOMIC_RELAXED, __HIP_MEMORY_SCOPE_AGENT);
      if (t + 1 >= T_) break;
      #pragma unroll
      for (int i = 0; i < 6; ++i) xbuf[tid + i * 256] = px[i];
      __syncthreads();                             // S3: xbuf = x(t+1)
      #pragma unroll
      for (int i = 0; i < 8; ++i) Ax[i] = 0.f;
      {
        const float4* x4 = (const float4*)xbuf;
        #pragma unroll
        for (int i = 0; i < 48; ++i) {
          int k = kq * 48 + i;
          float4 a = x4[k * 2], b = x4[k * 2 + 1];
          FMA_8(Ax, wx[i], a, b);
        }
      }
      if (tid < 16) {                              // parallel 16-line detect
        const int* fp = flagsA + ((size_t)t * 16 + tid) * 32;
        while (aload32(fp) == 0) __builtin_amdgcn_s_sleep(1);
      }
      __syncthreads();                             // S4: all 16 published
      {
        const ull* s8 = (const ull*)(h0all + (size_t)t * 2048);
        ull* d8 = (ull*)hsf;
        #pragma unroll
        for (int i = 0; i < 4; ++i) d8[tid * 4 + i] = aload64(s8 + tid * 4 + i);
      }
      __syncthreads();                             // S5: hsf = h0(t)
    }
  } else {
    // ============================ G2: layer1 ============================
    const int wgl = wg - 16;
    float* xh0 = lds;             // 2048: h0(t) [k][e]
    float* hsf = lds + 2048;      // 2048: h1(t-1) [k][e]
    float* gl  = lds + 4096;      // 2048
    const float* wp = wt_p1 + wgl * 64 + r6;
    float wx[64], wh[64];
    #pragma unroll
    for (int i = 0; i < 64; ++i) wx[i] = wp[(size_t)(kq * 64 + i) * 1024];
    #pragma unroll
    for (int i = 0; i < 64; ++i) wh[i] = wp[(size_t)(256 + kq * 64 + i) * 1024];
    const int j = wgl * 16 + uj;
    float creg = 0.f, bi = 0.f, bff = 0.f, bg = 0.f, bo = 0.f;
    if (tid < 128) {
      creg = pre_c0[(ue * 2 + 1) * 256 + j];
      bi = b_p1[j]; bff = b_p1[256 + j]; bg = b_p1[512 + j]; bo = b_p1[768 + j];
    }
    for (int idx = tid; idx < 2048; idx += 256) {
      int k = idx >> 3, e = idx & 7;
      hsf[idx] = pre_h0[(e * 2 + 1) * 256 + k];
    }
    __syncthreads();
    if (tid < 16) {
      const int* fp = flagsA + (size_t)tid * 32;   // step 0 flags
      while (aload32(fp) == 0) __builtin_amdgcn_s_sleep(1);
    }
    __syncthreads();
    {
      const ull* s8 = (const ull*)h0all;
      ull* d8 = (ull*)xh0;
      #pragma unroll
      for (int i = 0; i < 4; ++i) d8[tid * 4 + i] = aload64(s8 + tid * 4 + i);
    }
    __syncthreads();
    float Ax[8] = {0,0,0,0,0,0,0,0};
    {
      const float4* x4 = (const float4*)xh0;
      #pragma unroll
      for (int i = 0; i < 64; ++i) {
        int kk = kq * 64 + i;
        float4 a = x4[kk * 2], b = x4[kk * 2 + 1];
        FMA_8(Ax, wx[i], a, b);
      }
    }
    for (int t = 0; t < T_; ++t) {
      float A[8];
      #pragma unroll
      for (int i = 0; i < 8; ++i) A[i] = Ax[i];
      {
        const float4* h4 = (const float4*)hsf;
        #pragma unroll
        for (int i = 0; i < 64; ++i) {
          int kk = kq * 64 + i;
          float4 a = h4[kk * 2], b = h4[kk * 2 + 1];
          FMA_8(A, wh[i], a, b);
        }
      }
      {
        float4* g4 = (float4*)gl;
        g4[(kq * 64 + r6) * 2]     = make_float4(A[0], A[1], A[2], A[3]);
        g4[(kq * 64 + r6) * 2 + 1] = make_float4(A[4], A[5], A[6], A[7]);
      }
      __syncthreads();                             // S1
      if (tid < 128) {
        float s0 = 0.f, s1 = 0.f, s2 = 0.f, s3 = 0.f;
        #pragma unroll
        for (int q = 0; q < 4; ++q) {
          s0 += gl[q * 512 + tid];       s1 += gl[q * 512 + 128 + tid];
          s2 += gl[q * 512 + 256 + tid]; s3 += gl[q * 512 + 384 + tid];
        }
        float c2 = sigm(s1 + bff) * creg + sigm(s0 + bi) * tanh_(s2 + bg);
        float h2 = sigm(s3 + bo) * tanh_(c2);
        creg = c2;
        __hip_atomic_store(&h1all[(size_t)t * 2048 + wgl * 128 + tid], h2,
                           __ATOMIC_RELAXED, __HIP_MEMORY_SCOPE_AGENT);
      }
      __syncthreads();                             // S2: publish drained
      if (tid == 0)
        __hip_atomic_store(&flagsB[((size_t)t * 16 + wgl) * 32], 1,
                           __ATOMIC_RELAXED, __HIP_MEMORY_SCOPE_AGENT);
      if (t + 1 >= T_) break;
      if (tid < 16) {                              // h0(t+1): G1 runs ahead
        const int* fp = flagsA + ((size_t)(t + 1) * 16 + tid) * 32;
        while (aload32(fp) == 0) __builtin_amdgcn_s_sleep(1);
      }
      __syncthreads();                             // S3
      {
        const ull* s8 = (const ull*)(h0all + (size_t)(t + 1) * 2048);
        ull* d8 = (ull*)xh0;
        #pragma unroll
        for (int i = 0; i < 4; ++i) d8[tid * 4 + i] = aload64(s8 + tid * 4 + i);
      }
      __syncthreads();                             // S4: xh0 = h0(t+1)
      #pragma unroll
      for (int i = 0; i < 8; ++i) Ax[i] = 0.f;
      {
        const float4* x4 = (const float4*)xh0;
        #pragma unroll
        for (int i = 0; i < 64; ++i) {
          int kk = kq * 64 + i;
          float4 a = x4[kk * 2], b = x4[kk * 2 + 1];
          FMA_8(Ax, wx[i], a, b);
        }
      }
      if (tid < 16) {                              // own group: long satisfied
        const int* fp = flagsB + ((size_t)t * 16 + tid) * 32;
        while (aload32(fp) == 0) __builtin_amdgcn_s_sleep(1);
      }
      __syncthreads();                             // S5
      {
        const ull* s8 = (const ull*)(h1all + (size_t)t * 2048);
        ull* d8 = (ull*)hsf;
        #pragma unroll
        for (int i = 0; i < 4; ++i) d8[tid * 4 + i] = aload64(s8 + tid * 4 + i);
      }
      __syncthreads();                             // S6: hsf = h1(t)
    }
  }
}

// ---------------------------------------------------------------------------
// fcK: parallel over t. pre_out[t][e][c] = leaky(Wfc @ h1all[t] + bfc)
// ---------------------------------------------------------------------------
__global__ void fcK(const float* __restrict__ h1all, const float* __restrict__ Wfc,
                    const float* __restrict__ bfc, float* __restrict__ pre_out) {
  __shared__ float hl[2048];
  const int t = blockIdx.x, tid = threadIdx.x;
  for (int idx = tid; idx < 2048; idx += 256) hl[idx] = h1all[(size_t)t * 2048 + idx];
  __syncthreads();
  const int c = tid >> 1, half = tid & 1;
  float b = bfc[c];
  float acc[4] = {b, b, b, b};
  const float4* h4 = (const float4*)hl;
  const float* wrow = Wfc + c * 256;
  #pragma unroll 4
  for (int k = 0; k < 256; ++k) {
    float w = wrow[k];
    float4 x = h4[k * 2 + half];
    acc[0] = fmaf(w, x.x, acc[0]); acc[1] = fmaf(w, x.y, acc[1]);
    acc[2] = fmaf(w, x.z, acc[2]); acc[3] = fmaf(w, x.w, acc[3]);
  }
  #pragma unroll
  for (int i = 0; i < 4; ++i) {
    int e = half * 4 + i;
    float v = acc[i];
    v = (v > 0.f) ? v : 0.05f * v;
    pre_out[((size_t)t * 8 + e) * 128 + c] = v;
  }
}

// ---------------------------------------------------------------------------
// comm cell for phase B
// ---------------------------------------------------------------------------
__device__ __forceinline__ void comm_cell(
    const float* __restrict__ wt, const float* __restrict__ bias,
    const float* xin, float* hL, float* cL, float* glb, float* hout,
    float alpha, int tid) {
  const int r = tid;
  float A0[8] = {0,0,0,0,0,0,0,0};
  float A1[8] = {0,0,0,0,0,0,0,0};
  const float4* x4 = (const float4*)xin;
  #pragma unroll 2
  for (int k = 0; k < 128; ++k) {
    float w0 = wt[k * 512 + r];
    float w1 = wt[k * 512 + 256 + r];
    float4 a = x4[k * 2], b = x4[k * 2 + 1];
    FMA_8(A0, w0, a, b);
    FMA_8(A1, w1, a, b);
  }
  const float4* h4 = (const float4*)hL;
  #pragma unroll 2
  for (int k = 0; k < 128; ++k) {
    float w0 = wt[(128 + k) * 512 + r];
    float w1 = wt[(128 + k) * 512 + 256 + r];
    float4 a = h4[k * 2], b = h4[k * 2 + 1];
    FMA_8(A0, w0, a, b);
    FMA_8(A1, w1, a, b);
  }
  {
    float4* g4 = (float4*)glb;
    g4[r * 2]             = make_float4(A0[0], A0[1], A0[2], A0[3]);
    g4[r * 2 + 1]         = make_float4(A0[4], A0[5], A0[6], A0[7]);
    g4[(256 + r) * 2]     = make_float4(A1[0], A1[1], A1[2], A1[3]);
    g4[(256 + r) * 2 + 1] = make_float4(A1[4], A1[5], A1[6], A1[7]);
  }
  __syncthreads();
  for (int idx = tid; idx < 1024; idx += 256) {
    int jj = idx >> 3, tt = idx & 7;
    float gi = glb[jj * 8 + tt]         + bias[jj];
    float gf = glb[(128 + jj) * 8 + tt] + bias[128 + jj];
    float gg = glb[(256 + jj) * 8 + tt] + bias[256 + jj];
    float go = glb[(384 + jj) * 8 + tt] + bias[384 + jj];
    float cold = cL[idx], hold = hL[idx];
    float c2 = sigm(gf) * cold + sigm(gi) * tanh_(gg);
    float h2 = sigm(go) * tanh_(c2);
    float hb = fmaf(alpha, h2 - hold, hold);
    float cb = fmaf(alpha, c2 - cold, cold);
    hL[idx] = hb; cL[idx] = cb;
    if (hout) hout[idx] = hb;
  }
  __syncthreads();
}

// ---------------------------------------------------------------------------
// phaseB: parallel over t (8 timesteps / WG); emits opre1 (incl. b_o)
// ---------------------------------------------------------------------------
__launch_bounds__(256, 2)
__global__ void phaseB(const float* __restrict__ pre_out,
                       const float* __restrict__ wt_c0, const float* __restrict__ wt_c1,
                       const float* __restrict__ b_c0, const float* __restrict__ b_c1,
                       const float* __restrict__ wt_o1, const float* __restrict__ b_o,
                       float* __restrict__ opre1) {
  __shared__ float pol[128 * 8];
  __shared__ float ch0[128 * 8], cc0[128 * 8], ch1[128 * 8], cc1[128 * 8];
  __shared__ float h0b[128 * 8];
  __shared__ float glb[512 * 8];
  const int wg = blockIdx.x, tid = threadIdx.x;
  const int t0 = wg * 8;
  for (int idx = tid; idx < 1024; idx += 256) { ch0[idx]=0.f; cc0[idx]=0.f; ch1[idx]=0.f; cc1[idx]=0.f; }
  __syncthreads();
  float alpha = 1.0f;
  for (int rd = 0; rd < 3; ++rd) {
    for (int e = 0; e < E_; ++e) {
      for (int idx = tid; idx < 1024; idx += 256) {
        int tt = idx >> 7, k = idx & 127;
        pol[k * 8 + tt] = pre_out[(((size_t)(t0 + tt)) * 8 + e) * 128 + k];
      }
      __syncthreads();
      comm_cell(wt_c0, b_c0, pol, ch0, cc0, glb, h0b, alpha, tid);
      comm_cell(wt_c1, b_c1, h0b, ch1, cc1, glb, nullptr, alpha, tid);
    }
    alpha *= 0.333f;
  }
  {
    const int r = tid;
    float A0[8], A1[8];
    #pragma unroll
    for (int tt = 0; tt < 8; ++tt) { A0[tt] = b_o[r]; A1[tt] = b_o[256 + r]; }
    const float4* c04 = (const float4*)cc0;
    const float4* c14 = (const float4*)cc1;
    #pragma unroll 2
    for (int k = 0; k < 128; ++k) {
      float w0 = wt_o1[k * 512 + r], w1 = wt_o1[k * 512 + 256 + r];
      float4 a = c04[k * 2], b = c04[k * 2 + 1];
      FMA_8(A0, w0, a, b);
      FMA_8(A1, w1, a, b);
    }
    #pragma unroll 2
    for (int k = 0; k < 128; ++k) {
      float w0 = wt_o1[(128 + k) * 512 + r], w1 = wt_o1[(128 + k) * 512 + 256 + r];
      float4 a = c14[k * 2], b = c14[k * 2 + 1];
      FMA_8(A0, w0, a, b);
      FMA_8(A1, w1, a, b);
    }
    #pragma unroll
    for (int tt = 0; tt < 8; ++tt) {
      opre1[((size_t)(t0 + tt)) * 512 + r]       = A0[tt];
      opre1[((size_t)(t0 + tt)) * 512 + 256 + r] = A1[tt];
    }
  }
}

// ---------------------------------------------------------------------------
// phaseC: 8 WGs, one per ensemble e. No inter-WG sync; Whh_o in registers.
// ---------------------------------------------------------------------------
__launch_bounds__(256, 1)
__global__ void phaseC(const float* __restrict__ opre1, const __hip_bfloat16* __restrict__ opre2,
                       const float* __restrict__ Whh_o, const float* __restrict__ out_h0,
                       const float* __restrict__ out_c0, float* __restrict__ oh_g) {
  __shared__ float ohl[128];
  __shared__ float gl[512];
  const int e = blockIdx.x, tid = threadIdx.x;
  const int r0 = tid, r1 = tid + 256;
  float w0[128], w1[128];
  #pragma unroll
  for (int k = 0; k < 128; ++k) w0[k] = Whh_o[r0 * 128 + k];
  #pragma unroll
  for (int k = 0; k < 128; ++k) w1[k] = Whh_o[r1 * 128 + k];
  if (tid < 128) ohl[tid] = out_h0[e * 128 + tid];
  float creg = (tid < 128) ? out_c0[e * 128 + tid] : 0.f;
  __syncthreads();
  float p0a = opre1[r0], p0b = opre1[r1];
  float q0a = __bfloat162float(opre2[(size_t)e * 512 + r0]);
  float q0b = __bfloat162float(opre2[(size_t)e * 512 + r1]);
  for (int t = 0; t < T_; ++t) {
    float a0 = p0a + q0a, a1 = p0b + q0b;
    if (t + 1 < T_) {
      p0a = opre1[(size_t)(t + 1) * 512 + r0];
      p0b = opre1[(size_t)(t + 1) * 512 + r1];
      q0a = __bfloat162float(opre2[((size_t)(t + 1) * 8 + e) * 512 + r0]);
      q0b = __bfloat162float(opre2[((size_t)(t + 1) * 8 + e) * 512 + r1]);
    }
    const float4* o4 = (const float4*)ohl;
    #pragma unroll
    for (int kk = 0; kk < 32; ++kk) {
      float4 x = o4[kk];
      a0 = fmaf(w0[kk * 4 + 0], x.x, a0); a0 = fmaf(w0[kk * 4 + 1], x.y, a0);
      a0 = fmaf(w0[kk * 4 + 2], x.z, a0); a0 = fmaf(w0[kk * 4 + 3], x.w, a0);
      a1 = fmaf(w1[kk * 4 + 0], x.x, a1); a1 = fmaf(w1[kk * 4 + 1], x.y, a1);
      a1 = fmaf(w1[kk * 4 + 2], x.z, a1); a1 = fmaf(w1[kk * 4 + 3], x.w, a1);
    }
    gl[r0] = a0; gl[r1] = a1;
    __syncthreads();
    if (tid < 128) {
      float gi = gl[tid], gf = gl[128 + tid], gg = gl[256 + tid], go = gl[384 + tid];
      float c2 = sigm(gf) * creg + sigm(gi) * tanh_(gg);
      float h2 = sigm(go) * tanh_(c2);
      creg = c2;
      ohl[tid] = h2;
      oh_g[(size_t)t * 1024 + e * 128 + tid] = h2;
    }
    __syncthreads();
  }
}

// ---------------------------------------------------------------------------
// phaseD: parallel over t: softmaxes
// ---------------------------------------------------------------------------
__global__ void phaseD(const float* __restrict__ oh_g,
                       const float* __restrict__ Wtar, const float* __restrict__ btar,
                       const float* __restrict__ Wdir, const float* __restrict__ bdir,
                       float* __restrict__ outp) {
  __shared__ float ohl[1024];
  const int t = blockIdx.x, tid = threadIdx.x;  // 64 threads
  for (int idx = tid; idx < 1024; idx += 64) ohl[idx] = oh_g[(size_t)t * 1024 + idx];
  __syncthreads();
  const int f = tid;
  for (int e = 0; e < E_; ++e) {
    float acc = btar[f];
    const float* wr = Wtar + f * 128;
    #pragma unroll 4
    for (int k = 0; k < 128; ++k) acc = fmaf(wr[k], ohl[e * 128 + k], acc);
    float m = acc;
    #pragma unroll
    for (int off = 32; off; off >>= 1) m = fmaxf(m, __shfl_xor(m, off, 64));
    float ex = __expf(acc - m);
    float s = ex;
    #pragma unroll
    for (int off = 32; off; off >>= 1) s += __shfl_xor(s, off, 64);
    outp[((size_t)t * 8 + e) * 64 + f] = ex / s;
  }
  if (tid < 8) {
    int e = tid;
    float d0 = bdir[0], d1 = bdir[1], d2 = bdir[2];
    #pragma unroll 4
    for (int k = 0; k < 128; ++k) {
      float x = ohl[e * 128 + k];
      d0 = fmaf(Wdir[k], x, d0);
      d1 = fmaf(Wdir[128 + k], x, d1);
      d2 = fmaf(Wdir[256 + k], x, d2);
    }
    float m = fmaxf(d0, fmaxf(d1, d2));
    float x0 = __expf(d0 - m), x1 = __expf(d1 - m), x2 = __expf(d2 - m);
    float s = x0 + x1 + x2;
    float* dp = outp + (size_t)T_ * 8 * 64 + ((size_t)t * 8 + e) * 3;
    dp[0] = x0 / s; dp[1] = x1 / s; dp[2] = x2 / s;
  }
}

extern "C" void kernel_launch(void* const* d_in, const int* in_sizes, int n_in,
                              void* d_out, int out_size, void* d_ws, size_t ws_size,
                              hipStream_t stream) {
  (void)in_sizes; (void)n_in; (void)out_size; (void)ws_size;
  const float* feat   = (const float*)d_in[0];
  const float* pre_h0 = (const float*)d_in[1];
  const float* pre_c0 = (const float*)d_in[2];
  const float* out_h0 = (const float*)d_in[3];
  const float* out_c0 = (const float*)d_in[4];
  const float* Wih_p0 = (const float*)d_in[5];
  const float* Whh_p0 = (const float*)d_in[6];
  const float* b_p0   = (const float*)d_in[7];
  const float* Wih_p1 = (const float*)d_in[8];
  const float* Whh_p1 = (const float*)d_in[9];
  const float* b_p1   = (const float*)d_in[10];
  const float* Wfc    = (const float*)d_in[11];
  const float* bfc    = (const float*)d_in[12];
  const float* Wih_c0 = (const float*)d_in[13];
  const float* Whh_c0 = (const float*)d_in[14];
  const float* b_c0   = (const float*)d_in[15];
  const float* Wih_c1 = (const float*)d_in[16];
  const float* Whh_c1 = (const float*)d_in[17];
  const float* b_c1   = (const float*)d_in[18];
  const float* Wih_o  = (const float*)d_in[19];
  const float* Whh_o  = (const float*)d_in[20];
  const float* b_o    = (const float*)d_in[21];
  const float* Wtar   = (const float*)d_in[22];
  const float* btar   = (const float*)d_in[23];
  const float* Wdir   = (const float*)d_in[24];
  const float* bdir   = (const float*)d_in[25];
  float* outp = (float*)d_out;

  float* ws = (float*)d_ws;
  size_t off = 0;
  float* pre_outB = ws + off; off += (size_t)T_ * E_ * 128;
  float* opre1    = ws + off; off += (size_t)T_ * 512;
  float* oh_g     = ws + off; off += (size_t)T_ * E_ * 128;
  float* wt_p0    = ws + off; off += (size_t)448 * 1024;
  float* wt_p1    = ws + off; off += (size_t)512 * 1024;
  float* wt_c0    = ws + off; off += (size_t)256 * 512;
  float* wt_c1    = ws + off; off += (size_t)256 * 512;
  float* wt_o1    = ws + off; off += (size_t)256 * 512;
  float* wt_o2    = ws + off; off += (size_t)192 * 512;
  __hip_bfloat16* opre2 = (__hip_bfloat16*)(ws + off);
  off += (size_t)T_ * E_ * 512 / 2;
  float* h0all = ws + off; off += (size_t)T_ * 2048;
  float* h1all = ws + off; off += (size_t)T_ * 2048;
  int* flags   = (int*)(ws + off);              // 2 * T * 16 * 32 ints (16 MB)
  int* flagsA  = flags;
  int* flagsB  = flags + (size_t)T_ * 16 * 32;

  initK<<<dim3(1024), dim3(256), 0, stream>>>(
      Wih_p0, Whh_p0, Wih_p1, Whh_p1, Wih_c0, Whh_c0, Wih_c1, Whh_c1, Wih_o,
      wt_p0, wt_p1, wt_c0, wt_c1, wt_o1, wt_o2, flags);
  opre2K<<<dim3(T_), dim3(256), 0, stream>>>(feat, wt_o2, opre2);
  phaseA<<<dim3(32), dim3(256), 0, stream>>>(
      feat, pre_h0, pre_c0, wt_p0, wt_p1, b_p0, b_p1, h0all, h1all, flagsA, flagsB);
  fcK<<<dim3(T_), dim3(256), 0, stream>>>(h1all, Wfc, bfc, pre_outB);
  phaseB<<<dim3(T_ / 8), dim3(256), 0, stream>>>(
      pre_outB, wt_c0, wt_c1, b_c0, b_c1, wt_o1, b_o, opre1);
  phaseC<<<dim3(E_), dim3(256), 0, stream>>>(
      opre1, opre2, Whh_o, out_h0, out_c0, oh_g);
  phaseD<<<dim3(T_), dim3(64), 0, stream>>>(oh_g, Wtar, btar, Wdir, bdir, outp);
}

// Round 6
// 36983.597 us; speedup vs baseline: 2.8025x; 2.7329x over previous
//
#include <hip/hip_runtime.h>
#include <hip/hip_bf16.h>

// Sizes from the reference
#define T_   4096
#define E_   8

typedef unsigned long long ull;

__device__ __forceinline__ float sigm(float x)  { return 1.0f / (1.0f + __expf(-x)); }
__device__ __forceinline__ float tanh_(float x) { return 1.0f - 2.0f / (__expf(2.0f * x) + 1.0f); }

__device__ __forceinline__ ull aload64(const ull* p) {
  return __hip_atomic_load(p, __ATOMIC_RELAXED, __HIP_MEMORY_SCOPE_AGENT);
}
__device__ __forceinline__ int aload32(const int* p) {
  return __hip_atomic_load(p, __ATOMIC_RELAXED, __HIP_MEMORY_SCOPE_AGENT);
}

#define FMA_8(ACC, W, VA, VB)                                   \
  ACC[0] = fmaf((W), (VA).x, ACC[0]); ACC[1] = fmaf((W), (VA).y, ACC[1]); \
  ACC[2] = fmaf((W), (VA).z, ACC[2]); ACC[3] = fmaf((W), (VA).w, ACC[3]); \
  ACC[4] = fmaf((W), (VB).x, ACC[4]); ACC[5] = fmaf((W), (VB).y, ACC[5]); \
  ACC[6] = fmaf((W), (VB).z, ACC[6]); ACC[7] = fmaf((W), (VB).w, ACC[7]);

// ---------------------------------------------------------------------------
// initK: K-major packed weight copies + zero flag arrays.
// wt_p0 PACKED: [k][c] c = wg*64 + r6 (r6 = gate*16+jl, orig col = gate*256+wg*16+jl)
//   k<192 = Wih_p0, else Whh_p0(k-192).  wt_p1 same packing, k<256 ih else hh.
// wt_c0/wt_c1[k][512]; wt_o1[k][512]=Wih_o[:,k] (k<256); wt_o2[k][512]=Wih_o[:,256+k]
// flagsA/flagsB: one 128-B line per (t, wg): index (t*16+wg)*32.
// ---------------------------------------------------------------------------
__global__ void initK(const float* __restrict__ Wih_p0, const float* __restrict__ Whh_p0,
                      const float* __restrict__ Wih_p1, const float* __restrict__ Whh_p1,
                      const float* __restrict__ Wih_c0, const float* __restrict__ Whh_c0,
                      const float* __restrict__ Wih_c1, const float* __restrict__ Whh_c1,
                      const float* __restrict__ Wih_o,
                      float* wt_p0, float* wt_p1, float* wt_c0, float* wt_c1,
                      float* wt_o1, float* wt_o2, int* flags) {
  const int NW = 458752 + 524288 + 131072 + 131072 + 131072 + 98304;
  const int NF = 2 * T_ * 16 * 32;
  const int NTOT = NW + NF;
  const int gsz = gridDim.x * blockDim.x;
  for (int i = blockIdx.x * blockDim.x + threadIdx.x; i < NTOT; i += gsz) {
    int idx = i;
    if (idx < 458752) { int k = idx >> 10, c = idx & 1023;
      int wg = c >> 6, r6 = c & 63, gate = r6 >> 4, jl = r6 & 15;
      int col = gate * 256 + wg * 16 + jl;
      wt_p0[idx] = (k < 192) ? Wih_p0[col * 192 + k] : Whh_p0[col * 256 + (k - 192)]; continue; }
    idx -= 458752;
    if (idx < 524288) { int k = idx >> 10, c = idx & 1023;
      int wg = c >> 6, r6 = c & 63, gate = r6 >> 4, jl = r6 & 15;
      int col = gate * 256 + wg * 16 + jl;
      wt_p1[idx] = (k < 256) ? Wih_p1[col * 256 + k] : Whh_p1[col * 256 + (k - 256)]; continue; }
    idx -= 524288;
    if (idx < 131072) { int k = idx >> 9, r = idx & 511;
      wt_c0[idx] = (k < 128) ? Wih_c0[r * 128 + k] : Whh_c0[r * 128 + (k - 128)]; continue; }
    idx -= 131072;
    if (idx < 131072) { int k = idx >> 9, r = idx & 511;
      wt_c1[idx] = (k < 128) ? Wih_c1[r * 128 + k] : Whh_c1[r * 128 + (k - 128)]; continue; }
    idx -= 131072;
    if (idx < 131072) { int k = idx >> 9, r = idx & 511;
      wt_o1[idx] = Wih_o[r * 448 + k]; continue; }
    idx -= 131072;
    if (idx < 98304) { int k = idx >> 9, r = idx & 511;
      wt_o2[idx] = Wih_o[r * 448 + 256 + k]; continue; }
    idx -= 98304;
    flags[idx] = 0;
  }
}

// ---------------------------------------------------------------------------
// opre2K: parallel over t. opre2[t][e][512] = Wih_o[:,256:448] @ x(t,e)  (bf16)
// ---------------------------------------------------------------------------
__global__ void opre2K(const float* __restrict__ feat, const float* __restrict__ wt_o2,
                       __hip_bfloat16* __restrict__ opre2) {
  __shared__ float xb[192 * 8];
  const int t = blockIdx.x, tid = threadIdx.x;
  const float* ft = feat + (size_t)t * 640;
  for (int idx = tid; idx < 192 * 8; idx += 256) {
    int k = idx >> 3, e = idx & 7;
    xb[idx] = (k < 128) ? ft[k] : ft[128 + e * 64 + (k - 128)];
  }
  __syncthreads();
  const int r = tid;
  float A0[8] = {0,0,0,0,0,0,0,0};
  float A1[8] = {0,0,0,0,0,0,0,0};
  const float4* x4 = (const float4*)xb;
  #pragma unroll 2
  for (int k = 0; k < 192; ++k) {
    float w0 = wt_o2[k * 512 + r];
    float w1 = wt_o2[k * 512 + 256 + r];
    float4 a = x4[k * 2], b = x4[k * 2 + 1];
    FMA_8(A0, w0, a, b);
    FMA_8(A1, w1, a, b);
  }
  #pragma unroll
  for (int e = 0; e < 8; ++e) {
    opre2[((size_t)t * 8 + e) * 512 + r]       = __float2bfloat16(A0[e]);
    opre2[((size_t)t * 8 + e) * 512 + 256 + r] = __float2bfloat16(A1[e]);
  }
}

// ---------------------------------------------------------------------------
// phaseA: 32 WGs. WG 0-15 = G1 (layer0), WG 16-31 = G2 (layer1, trailing).
// Weights STREAM from L2 (r3 structure: VGPR ~68, loads pipeline under FMAs —
// the 256-VGPR register-weight variant spilled to scratch and was 3x slower).
// Exchange: relaxed agent stores drained by __syncthreads (vmcnt0 before
// s_barrier), then one flag store per WG per step on its OWN 128-B line;
// detect = parallel poll of independent lines (single RTT, no RMW queue).
// G2 polls both dependencies in ONE combined loop (lanes 0-15: flagsA(t+1),
// lanes 16-31: flagsB(t)) and issues both gathers back-to-back.
// ---------------------------------------------------------------------------
__launch_bounds__(256, 1)
__global__ void phaseA(const float* __restrict__ feat,
                       const float* __restrict__ pre_h0, const float* __restrict__ pre_c0,
                       const float* __restrict__ wt_p0, const float* __restrict__ wt_p1,
                       const float* __restrict__ b_p0, const float* __restrict__ b_p1,
                       float* __restrict__ h0all, float* __restrict__ h1all,
                       int* __restrict__ flagsA, int* __restrict__ flagsB) {
  __shared__ float lds[6144];
  const int wg = blockIdx.x, tid = threadIdx.x;
  const int r6 = tid & 63, kq = tid >> 6;
  const int uj = tid >> 3, ue = tid & 7;

  if (wg < 16) {
    // ============================ G1: layer0 ============================
    float* xbuf = lds;            // 1536: x(t) [k][e]
    float* hsf  = lds + 1536;     // 2048: h0(t-1) [k][e]
    float* gl   = lds + 3584;     // 2048: partials
    const float* wp = wt_p0 + wg * 64 + r6;
    const int j = wg * 16 + uj;
    float creg = 0.f, bi = 0.f, bff = 0.f, bg = 0.f, bo = 0.f;
    if (tid < 128) {
      creg = pre_c0[(ue * 2 + 0) * 256 + j];
      bi = b_p0[j]; bff = b_p0[256 + j]; bg = b_p0[512 + j]; bo = b_p0[768 + j];
    }
    for (int idx = tid; idx < 2048; idx += 256) {
      int k = idx >> 3, e = idx & 7;
      hsf[idx] = pre_h0[(e * 2 + 0) * 256 + k];
    }
    for (int idx = tid; idx < 1536; idx += 256) {
      int k = idx >> 3, e = idx & 7;
      xbuf[idx] = (k < 128) ? feat[k] : feat[128 + e * 64 + (k - 128)];
    }
    __syncthreads();
    float Ax[8] = {0,0,0,0,0,0,0,0};
    {
      const float4* x4 = (const float4*)xbuf;
      #pragma unroll 8
      for (int k = kq * 48; k < kq * 48 + 48; ++k) {
        float w = wp[k * 1024];
        float4 a = x4[k * 2], b = x4[k * 2 + 1];
        FMA_8(Ax, w, a, b);
      }
    }
    for (int t = 0; t < T_; ++t) {
      float px[6];
      if (t + 1 < T_) {
        const float* ft1 = feat + (size_t)(t + 1) * 640;
        #pragma unroll
        for (int i = 0; i < 6; ++i) {
          int idx = tid + i * 256; int k = idx >> 3, e = idx & 7;
          px[i] = (k < 128) ? ft1[k] : ft1[128 + e * 64 + (k - 128)];
        }
      }
      float A[8];
      #pragma unroll
      for (int i = 0; i < 8; ++i) A[i] = Ax[i];
      {  // h-part: k in [192+kq*64, +64), weights stream from L2
        const float4* h4 = (const float4*)hsf;
        const int kb = 192 + kq * 64;
        #pragma unroll 8
        for (int k = kb; k < kb + 64; ++k) {
          float w = wp[k * 1024];
          int kk = k - 192;
          float4 a = h4[kk * 2], b = h4[kk * 2 + 1];
          FMA_8(A, w, a, b);
        }
      }
      {
        float4* g4 = (float4*)gl;
        g4[(kq * 64 + r6) * 2]     = make_float4(A[0], A[1], A[2], A[3]);
        g4[(kq * 64 + r6) * 2 + 1] = make_float4(A[4], A[5], A[6], A[7]);
      }
      __syncthreads();                             // S1: gl ready
      if (tid < 128) {
        float s0 = 0.f, s1 = 0.f, s2 = 0.f, s3 = 0.f;
        #pragma unroll
        for (int q = 0; q < 4; ++q) {
          s0 += gl[q * 512 + tid];       s1 += gl[q * 512 + 128 + tid];
          s2 += gl[q * 512 + 256 + tid]; s3 += gl[q * 512 + 384 + tid];
        }
        float c2 = sigm(s1 + bff) * creg + sigm(s0 + bi) * tanh_(s2 + bg);
        float h2 = sigm(s3 + bo) * tanh_(c2);
        creg = c2;
        __hip_atomic_store(&h0all[(size_t)t * 2048 + wg * 128 + tid], h2,
                           __ATOMIC_RELAXED, __HIP_MEMORY_SCOPE_AGENT);
      }
      __syncthreads();                             // S2: publish drained (vmcnt0)
      if (tid == 0)
        __hip_atomic_store(&flagsA[((size_t)t * 16 + wg) * 32], 1,
                           __ATOMIC_RELAXED, __HIP_MEMORY_SCOPE_AGENT);
      if (t + 1 >= T_) break;
      #pragma unroll
      for (int i = 0; i < 6; ++i) xbuf[tid + i * 256] = px[i];
      __syncthreads();                             // S3: xbuf = x(t+1)
      #pragma unroll
      for (int i = 0; i < 8; ++i) Ax[i] = 0.f;
      {  // x-part of t+1 in the sync shadow
        const float4* x4 = (const float4*)xbuf;
        #pragma unroll 8
        for (int k = kq * 48; k < kq * 48 + 48; ++k) {
          float w = wp[k * 1024];
          float4 a = x4[k * 2], b = x4[k * 2 + 1];
          FMA_8(Ax, w, a, b);
        }
      }
      if (tid < 16) {                              // parallel 16-line detect
        const int* fp = flagsA + ((size_t)t * 16 + tid) * 32;
        while (aload32(fp) == 0) __builtin_amdgcn_s_sleep(1);
      }
      __syncthreads();                             // S4: all 16 published
      {
        const ull* s8 = (const ull*)(h0all + (size_t)t * 2048);
        ull* d8 = (ull*)hsf;
        #pragma unroll
        for (int i = 0; i < 4; ++i) d8[tid * 4 + i] = aload64(s8 + tid * 4 + i);
      }
      __syncthreads();                             // S5: hsf = h0(t)
    }
  } else {
    // ============================ G2: layer1 ============================
    const int wgl = wg - 16;
    float* xh0 = lds;             // 2048: h0(t) [k][e]
    float* hsf = lds + 2048;      // 2048: h1(t-1) [k][e]
    float* gl  = lds + 4096;      // 2048
    const float* wp = wt_p1 + wgl * 64 + r6;
    const int j = wgl * 16 + uj;
    float creg = 0.f, bi = 0.f, bff = 0.f, bg = 0.f, bo = 0.f;
    if (tid < 128) {
      creg = pre_c0[(ue * 2 + 1) * 256 + j];
      bi = b_p1[j]; bff = b_p1[256 + j]; bg = b_p1[512 + j]; bo = b_p1[768 + j];
    }
    for (int idx = tid; idx < 2048; idx += 256) {
      int k = idx >> 3, e = idx & 7;
      hsf[idx] = pre_h0[(e * 2 + 1) * 256 + k];
    }
    __syncthreads();
    if (tid < 16) {
      const int* fp = flagsA + (size_t)tid * 32;   // step 0 flags
      while (aload32(fp) == 0) __builtin_amdgcn_s_sleep(1);
    }
    __syncthreads();
    {
      const ull* s8 = (const ull*)h0all;
      ull* d8 = (ull*)xh0;
      #pragma unroll
      for (int i = 0; i < 4; ++i) d8[tid * 4 + i] = aload64(s8 + tid * 4 + i);
    }
    __syncthreads();
    float Ax[8] = {0,0,0,0,0,0,0,0};
    {
      const float4* x4 = (const float4*)xh0;
      #pragma unroll 8
      for (int k = kq * 64; k < kq * 64 + 64; ++k) {
        float w = wp[k * 1024];
        float4 a = x4[(k - kq * 64 + kq * 64) * 2], b = x4[k * 2 + 1];
        // (identical to x4[k*2]; spelled plainly below)
        a = x4[k * 2];
        FMA_8(Ax, w, a, b);
      }
    }
    for (int t = 0; t < T_; ++t) {
      float A[8];
      #pragma unroll
      for (int i = 0; i < 8; ++i) A[i] = Ax[i];
      {  // h-part: k in [256+kq*64, +64), weights stream from L2
        const float4* h4 = (const float4*)hsf;
        const int kb = 256 + kq * 64;
        #pragma unroll 8
        for (int k = kb; k < kb + 64; ++k) {
          float w = wp[k * 1024];
          int kk = k - 256;
          float4 a = h4[kk * 2], b = h4[kk * 2 + 1];
          FMA_8(A, w, a, b);
        }
      }
      {
        float4* g4 = (float4*)gl;
        g4[(kq * 64 + r6) * 2]     = make_float4(A[0], A[1], A[2], A[3]);
        g4[(kq * 64 + r6) * 2 + 1] = make_float4(A[4], A[5], A[6], A[7]);
      }
      __syncthreads();                             // S1
      if (tid < 128) {
        float s0 = 0.f, s1 = 0.f, s2 = 0.f, s3 = 0.f;
        #pragma unroll
        for (int q = 0; q < 4; ++q) {
          s0 += gl[q * 512 + tid];       s1 += gl[q * 512 + 128 + tid];
          s2 += gl[q * 512 + 256 + tid]; s3 += gl[q * 512 + 384 + tid];
        }
        float c2 = sigm(s1 + bff) * creg + sigm(s0 + bi) * tanh_(s2 + bg);
        float h2 = sigm(s3 + bo) * tanh_(c2);
        creg = c2;
        __hip_atomic_store(&h1all[(size_t)t * 2048 + wgl * 128 + tid], h2,
                           __ATOMIC_RELAXED, __HIP_MEMORY_SCOPE_AGENT);
      }
      __syncthreads();                             // S2: publish drained
      if (tid == 0)
        __hip_atomic_store(&flagsB[((size_t)t * 16 + wgl) * 32], 1,
                           __ATOMIC_RELAXED, __HIP_MEMORY_SCOPE_AGENT);
      if (t + 1 >= T_) break;
      if (tid < 32) {                              // combined detect: one loop,
        const int* fp = (tid < 16)                 // both flag sets in flight
            ? flagsA + ((size_t)(t + 1) * 16 + tid) * 32
            : flagsB + ((size_t)t * 16 + (tid - 16)) * 32;
        while (aload32(fp) == 0) __builtin_amdgcn_s_sleep(1);
      }
      __syncthreads();                             // S3: both ready
      {                                            // both gathers back-to-back
        const ull* s0p = (const ull*)(h0all + (size_t)(t + 1) * 2048);
        const ull* s1p = (const ull*)(h1all + (size_t)t * 2048);
        ull v0[4], v1[4];
        #pragma unroll
        for (int i = 0; i < 4; ++i) v0[i] = aload64(s0p + tid * 4 + i);
        #pragma unroll
        for (int i = 0; i < 4; ++i) v1[i] = aload64(s1p + tid * 4 + i);
        ull* d0 = (ull*)xh0; ull* d1 = (ull*)hsf;
        #pragma unroll
        for (int i = 0; i < 4; ++i) { d0[tid * 4 + i] = v0[i]; d1[tid * 4 + i] = v1[i]; }
      }
      __syncthreads();                             // S4: xh0=h0(t+1), hsf=h1(t)
      #pragma unroll
      for (int i = 0; i < 8; ++i) Ax[i] = 0.f;
      {  // h0-part of t+1
        const float4* x4 = (const float4*)xh0;
        #pragma unroll 8
        for (int k = kq * 64; k < kq * 64 + 64; ++k) {
          float w = wp[k * 1024];
          float4 a = x4[k * 2], b = x4[k * 2 + 1];
          FMA_8(Ax, w, a, b);
        }
      }
    }
  }
}

// ---------------------------------------------------------------------------
// fcK: parallel over t. pre_out[t][e][c] = leaky(Wfc @ h1all[t] + bfc)
// ---------------------------------------------------------------------------
__global__ void fcK(const float* __restrict__ h1all, const float* __restrict__ Wfc,
                    const float* __restrict__ bfc, float* __restrict__ pre_out) {
  __shared__ float hl[2048];
  const int t = blockIdx.x, tid = threadIdx.x;
  for (int idx = tid; idx < 2048; idx += 256) hl[idx] = h1all[(size_t)t * 2048 + idx];
  __syncthreads();
  const int c = tid >> 1, half = tid & 1;
  float b = bfc[c];
  float acc[4] = {b, b, b, b};
  const float4* h4 = (const float4*)hl;
  const float* wrow = Wfc + c * 256;
  #pragma unroll 4
  for (int k = 0; k < 256; ++k) {
    float w = wrow[k];
    float4 x = h4[k * 2 + half];
    acc[0] = fmaf(w, x.x, acc[0]); acc[1] = fmaf(w, x.y, acc[1]);
    acc[2] = fmaf(w, x.z, acc[2]); acc[3] = fmaf(w, x.w, acc[3]);
  }
  #pragma unroll
  for (int i = 0; i < 4; ++i) {
    int e = half * 4 + i;
    float v = acc[i];
    v = (v > 0.f) ? v : 0.05f * v;
    pre_out[((size_t)t * 8 + e) * 128 + c] = v;
  }
}

// ---------------------------------------------------------------------------
// comm cell for phase B
// ---------------------------------------------------------------------------
__device__ __forceinline__ void comm_cell(
    const float* __restrict__ wt, const float* __restrict__ bias,
    const float* xin, float* hL, float* cL, float* glb, float* hout,
    float alpha, int tid) {
  const int r = tid;
  float A0[8] = {0,0,0,0,0,0,0,0};
  float A1[8] = {0,0,0,0,0,0,0,0};
  const float4* x4 = (const float4*)xin;
  #pragma unroll 2
  for (int k = 0; k < 128; ++k) {
    float w0 = wt[k * 512 + r];
    float w1 = wt[k * 512 + 256 + r];
    float4 a = x4[k * 2], b = x4[k * 2 + 1];
    FMA_8(A0, w0, a, b);
    FMA_8(A1, w1, a, b);
  }
  const float4* h4 = (const float4*)hL;
  #pragma unroll 2
  for (int k = 0; k < 128; ++k) {
    float w0 = wt[(128 + k) * 512 + r];
    float w1 = wt[(128 + k) * 512 + 256 + r];
    float4 a = h4[k * 2], b = h4[k * 2 + 1];
    FMA_8(A0, w0, a, b);
    FMA_8(A1, w1, a, b);
  }
  {
    float4* g4 = (float4*)glb;
    g4[r * 2]             = make_float4(A0[0], A0[1], A0[2], A0[3]);
    g4[r * 2 + 1]         = make_float4(A0[4], A0[5], A0[6], A0[7]);
    g4[(256 + r) * 2]     = make_float4(A1[0], A1[1], A1[2], A1[3]);
    g4[(256 + r) * 2 + 1] = make_float4(A1[4], A1[5], A1[6], A1[7]);
  }
  __syncthreads();
  for (int idx = tid; idx < 1024; idx += 256) {
    int jj = idx >> 3, tt = idx & 7;
    float gi = glb[jj * 8 + tt]         + bias[jj];
    float gf = glb[(128 + jj) * 8 + tt] + bias[128 + jj];
    float gg = glb[(256 + jj) * 8 + tt] + bias[256 + jj];
    float go = glb[(384 + jj) * 8 + tt] + bias[384 + jj];
    float cold = cL[idx], hold = hL[idx];
    float c2 = sigm(gf) * cold + sigm(gi) * tanh_(gg);
    float h2 = sigm(go) * tanh_(c2);
    float hb = fmaf(alpha, h2 - hold, hold);
    float cb = fmaf(alpha, c2 - cold, cold);
    hL[idx] = hb; cL[idx] = cb;
    if (hout) hout[idx] = hb;
  }
  __syncthreads();
}

// ---------------------------------------------------------------------------
// phaseB: parallel over t (8 timesteps / WG); emits opre1 (incl. b_o)
// ---------------------------------------------------------------------------
__launch_bounds__(256, 2)
__global__ void phaseB(const float* __restrict__ pre_out,
                       const float* __restrict__ wt_c0, const float* __restrict__ wt_c1,
                       const float* __restrict__ b_c0, const float* __restrict__ b_c1,
                       const float* __restrict__ wt_o1, const float* __restrict__ b_o,
                       float* __restrict__ opre1) {
  __shared__ float pol[128 * 8];
  __shared__ float ch0[128 * 8], cc0[128 * 8], ch1[128 * 8], cc1[128 * 8];
  __shared__ float h0b[128 * 8];
  __shared__ float glb[512 * 8];
  const int wg = blockIdx.x, tid = threadIdx.x;
  const int t0 = wg * 8;
  for (int idx = tid; idx < 1024; idx += 256) { ch0[idx]=0.f; cc0[idx]=0.f; ch1[idx]=0.f; cc1[idx]=0.f; }
  __syncthreads();
  float alpha = 1.0f;
  for (int rd = 0; rd < 3; ++rd) {
    for (int e = 0; e < E_; ++e) {
      for (int idx = tid; idx < 1024; idx += 256) {
        int tt = idx >> 7, k = idx & 127;
        pol[k * 8 + tt] = pre_out[(((size_t)(t0 + tt)) * 8 + e) * 128 + k];
      }
      __syncthreads();
      comm_cell(wt_c0, b_c0, pol, ch0, cc0, glb, h0b, alpha, tid);
      comm_cell(wt_c1, b_c1, h0b, ch1, cc1, glb, nullptr, alpha, tid);
    }
    alpha *= 0.333f;
  }
  {
    const int r = tid;
    float A0[8], A1[8];
    #pragma unroll
    for (int tt = 0; tt < 8; ++tt) { A0[tt] = b_o[r]; A1[tt] = b_o[256 + r]; }
    const float4* c04 = (const float4*)cc0;
    const float4* c14 = (const float4*)cc1;
    #pragma unroll 2
    for (int k = 0; k < 128; ++k) {
      float w0 = wt_o1[k * 512 + r], w1 = wt_o1[k * 512 + 256 + r];
      float4 a = c04[k * 2], b = c04[k * 2 + 1];
      FMA_8(A0, w0, a, b);
      FMA_8(A1, w1, a, b);
    }
    #pragma unroll 2
    for (int k = 0; k < 128; ++k) {
      float w0 = wt_o1[(128 + k) * 512 + r], w1 = wt_o1[(128 + k) * 512 + 256 + r];
      float4 a = c14[k * 2], b = c14[k * 2 + 1];
      FMA_8(A0, w0, a, b);
      FMA_8(A1, w1, a, b);
    }
    #pragma unroll
    for (int tt = 0; tt < 8; ++tt) {
      opre1[((size_t)(t0 + tt)) * 512 + r]       = A0[tt];
      opre1[((size_t)(t0 + tt)) * 512 + 256 + r] = A1[tt];
    }
  }
}

// ---------------------------------------------------------------------------
// phaseC: 8 WGs, one per ensemble e. No inter-WG sync; Whh_o in registers.
// ---------------------------------------------------------------------------
__launch_bounds__(256, 1)
__global__ void phaseC(const float* __restrict__ opre1, const __hip_bfloat16* __restrict__ opre2,
                       const float* __restrict__ Whh_o, const float* __restrict__ out_h0,
                       const float* __restrict__ out_c0, float* __restrict__ oh_g) {
  __shared__ float ohl[128];
  __shared__ float gl[512];
  const int e = blockIdx.x, tid = threadIdx.x;
  const int r0 = tid, r1 = tid + 256;
  float w0[128], w1[128];
  #pragma unroll
  for (int k = 0; k < 128; ++k) w0[k] = Whh_o[r0 * 128 + k];
  #pragma unroll
  for (int k = 0; k < 128; ++k) w1[k] = Whh_o[r1 * 128 + k];
  if (tid < 128) ohl[tid] = out_h0[e * 128 + tid];
  float creg = (tid < 128) ? out_c0[e * 128 + tid] : 0.f;
  __syncthreads();
  float p0a = opre1[r0], p0b = opre1[r1];
  float q0a = __bfloat162float(opre2[(size_t)e * 512 + r0]);
  float q0b = __bfloat162float(opre2[(size_t)e * 512 + r1]);
  for (int t = 0; t < T_; ++t) {
    float a0 = p0a + q0a, a1 = p0b + q0b;
    if (t + 1 < T_) {
      p0a = opre1[(size_t)(t + 1) * 512 + r0];
      p0b = opre1[(size_t)(t + 1) * 512 + r1];
      q0a = __bfloat162float(opre2[((size_t)(t + 1) * 8 + e) * 512 + r0]);
      q0b = __bfloat162float(opre2[((size_t)(t + 1) * 8 + e) * 512 + r1]);
    }
    const float4* o4 = (const float4*)ohl;
    #pragma unroll
    for (int kk = 0; kk < 32; ++kk) {
      float4 x = o4[kk];
      a0 = fmaf(w0[kk * 4 + 0], x.x, a0); a0 = fmaf(w0[kk * 4 + 1], x.y, a0);
      a0 = fmaf(w0[kk * 4 + 2], x.z, a0); a0 = fmaf(w0[kk * 4 + 3], x.w, a0);
      a1 = fmaf(w1[kk * 4 + 0], x.x, a1); a1 = fmaf(w1[kk * 4 + 1], x.y, a1);
      a1 = fmaf(w1[kk * 4 + 2], x.z, a1); a1 = fmaf(w1[kk * 4 + 3], x.w, a1);
    }
    gl[r0] = a0; gl[r1] = a1;
    __syncthreads();
    if (tid < 128) {
      float gi = gl[tid], gf = gl[128 + tid], gg = gl[256 + tid], go = gl[384 + tid];
      float c2 = sigm(gf) * creg + sigm(gi) * tanh_(gg);
      float h2 = sigm(go) * tanh_(c2);
      creg = c2;
      ohl[tid] = h2;
      oh_g[(size_t)t * 1024 + e * 128 + tid] = h2;
    }
    __syncthreads();
  }
}

// ---------------------------------------------------------------------------
// phaseD: parallel over t: softmaxes
// ---------------------------------------------------------------------------
__global__ void phaseD(const float* __restrict__ oh_g,
                       const float* __restrict__ Wtar, const float* __restrict__ btar,
                       const float* __restrict__ Wdir, const float* __restrict__ bdir,
                       float* __restrict__ outp) {
  __shared__ float ohl[1024];
  const int t = blockIdx.x, tid = threadIdx.x;  // 64 threads
  for (int idx = tid; idx < 1024; idx += 64) ohl[idx] = oh_g[(size_t)t * 1024 + idx];
  __syncthreads();
  const int f = tid;
  for (int e = 0; e < E_; ++e) {
    float acc = btar[f];
    const float* wr = Wtar + f * 128;
    #pragma unroll 4
    for (int k = 0; k < 128; ++k) acc = fmaf(wr[k], ohl[e * 128 + k], acc);
    float m = acc;
    #pragma unroll
    for (int off = 32; off; off >>= 1) m = fmaxf(m, __shfl_xor(m, off, 64));
    float ex = __expf(acc - m);
    float s = ex;
    #pragma unroll
    for (int off = 32; off; off >>= 1) s += __shfl_xor(s, off, 64);
    outp[((size_t)t * 8 + e) * 64 + f] = ex / s;
  }
  if (tid < 8) {
    int e = tid;
    float d0 = bdir[0], d1 = bdir[1], d2 = bdir[2];
    #pragma unroll 4
    for (int k = 0; k < 128; ++k) {
      float x = ohl[e * 128 + k];
      d0 = fmaf(Wdir[k], x, d0);
      d1 = fmaf(Wdir[128 + k], x, d1);
      d2 = fmaf(Wdir[256 + k], x, d2);
    }
    float m = fmaxf(d0, fmaxf(d1, d2));
    float x0 = __expf(d0 - m), x1 = __expf(d1 - m), x2 = __expf(d2 - m);
    float s = x0 + x1 + x2;
    float* dp = outp + (size_t)T_ * 8 * 64 + ((size_t)t * 8 + e) * 3;
    dp[0] = x0 / s; dp[1] = x1 / s; dp[2] = x2 / s;
  }
}

extern "C" void kernel_launch(void* const* d_in, const int* in_sizes, int n_in,
                              void* d_out, int out_size, void* d_ws, size_t ws_size,
                              hipStream_t stream) {
  (void)in_sizes; (void)n_in; (void)out_size; (void)ws_size;
  const float* feat   = (const float*)d_in[0];
  const float* pre_h0 = (const float*)d_in[1];
  const float* pre_c0 = (const float*)d_in[2];
  const float* out_h0 = (const float*)d_in[3];
  const float* out_c0 = (const float*)d_in[4];
  const float* Wih_p0 = (const float*)d_in[5];
  const float* Whh_p0 = (const float*)d_in[6];
  const float* b_p0   = (const float*)d_in[7];
  const float* Wih_p1 = (const float*)d_in[8];
  const float* Whh_p1 = (const float*)d_in[9];
  const float* b_p1   = (const float*)d_in[10];
  const float* Wfc    = (const float*)d_in[11];
  const float* bfc    = (const float*)d_in[12];
  const float* Wih_c0 = (const float*)d_in[13];
  const float* Whh_c0 = (const float*)d_in[14];
  const float* b_c0   = (const float*)d_in[15];
  const float* Wih_c1 = (const float*)d_in[16];
  const float* Whh_c1 = (const float*)d_in[17];
  const float* b_c1   = (const float*)d_in[18];
  const float* Wih_o  = (const float*)d_in[19];
  const float* Whh_o  = (const float*)d_in[20];
  const float* b_o    = (const float*)d_in[21];
  const float* Wtar   = (const float*)d_in[22];
  const float* btar   = (const float*)d_in[23];
  const float* Wdir   = (const float*)d_in[24];
  const float* bdir   = (const float*)d_in[25];
  float* outp = (float*)d_out;

  float* ws = (float*)d_ws;
  size_t off = 0;
  float* pre_outB = ws + off; off += (size_t)T_ * E_ * 128;
  float* opre1    = ws + off; off += (size_t)T_ * 512;
  float* oh_g     = ws + off; off += (size_t)T_ * E_ * 128;
  float* wt_p0    = ws + off; off += (size_t)448 * 1024;
  float* wt_p1    = ws + off; off += (size_t)512 * 1024;
  float* wt_c0    = ws + off; off += (size_t)256 * 512;
  float* wt_c1    = ws + off; off += (size_t)256 * 512;
  float* wt_o1    = ws + off; off += (size_t)256 * 512;
  float* wt_o2    = ws + off; off += (size_t)192 * 512;
  __hip_bfloat16* opre2 = (__hip_bfloat16*)(ws + off);
  off += (size_t)T_ * E_ * 512 / 2;
  float* h0all = ws + off; off += (size_t)T_ * 2048;
  float* h1all = ws + off; off += (size_t)T_ * 2048;
  int* flags   = (int*)(ws + off);              // 2 * T * 16 * 32 ints (16 MB)
  int* flagsA  = flags;
  int* flagsB  = flags + (size_t)T_ * 16 * 32;

  initK<<<dim3(1024), dim3(256), 0, stream>>>(
      Wih_p0, Whh_p0, Wih_p1, Whh_p1, Wih_c0, Whh_c0, Wih_c1, Whh_c1, Wih_o,
      wt_p0, wt_p1, wt_c0, wt_c1, wt_o1, wt_o2, flags);
  opre2K<<<dim3(T_), dim3(256), 0, stream>>>(feat, wt_o2, opre2);
  phaseA<<<dim3(32), dim3(256), 0, stream>>>(
      feat, pre_h0, pre_c0, wt_p0, wt_p1, b_p0, b_p1, h0all, h1all, flagsA, flagsB);
  fcK<<<dim3(T_), dim3(256), 0, stream>>>(h1all, Wfc, bfc, pre_outB);
  phaseB<<<dim3(T_ / 8), dim3(256), 0, stream>>>(
      pre_outB, wt_c0, wt_c1, b_c0, b_c1, wt_o1, b_o, opre1);
  phaseC<<<dim3(E_), dim3(256), 0, stream>>>(
      opre1, opre2, Whh_o, out_h0, out_c0, oh_g);
  phaseD<<<dim3(T_), dim3(64), 0, stream>>>(oh_g, Wtar, btar, Wdir, bdir, outp);
}

// Round 7
// 32579.471 us; speedup vs baseline: 3.1814x; 1.1352x over previous
//
#include <hip/hip_runtime.h>
#include <hip/hip_bf16.h>

// Sizes from the reference
#define T_   4096
#define E_   8

typedef unsigned long long ull;

__device__ __forceinline__ float sigm(float x)  { return 1.0f / (1.0f + __expf(-x)); }
__device__ __forceinline__ float tanh_(float x) { return 1.0f - 2.0f / (__expf(2.0f * x) + 1.0f); }

__device__ __forceinline__ ull aload64(const ull* p) {
  return __hip_atomic_load(p, __ATOMIC_RELAXED, __HIP_MEMORY_SCOPE_AGENT);
}
__device__ __forceinline__ int aload32(const int* p) {
  return __hip_atomic_load(p, __ATOMIC_RELAXED, __HIP_MEMORY_SCOPE_AGENT);
}

#define FMA_8(ACC, W, VA, VB)                                   \
  ACC[0] = fmaf((W), (VA).x, ACC[0]); ACC[1] = fmaf((W), (VA).y, ACC[1]); \
  ACC[2] = fmaf((W), (VA).z, ACC[2]); ACC[3] = fmaf((W), (VA).w, ACC[3]); \
  ACC[4] = fmaf((W), (VB).x, ACC[4]); ACC[5] = fmaf((W), (VB).y, ACC[5]); \
  ACC[6] = fmaf((W), (VB).z, ACC[6]); ACC[7] = fmaf((W), (VB).w, ACC[7]);

// ---------------------------------------------------------------------------
// initK: K-major packed weight copies + zero flag arrays. (unchanged from r6)
// ---------------------------------------------------------------------------
__global__ void initK(const float* __restrict__ Wih_p0, const float* __restrict__ Whh_p0,
                      const float* __restrict__ Wih_p1, const float* __restrict__ Whh_p1,
                      const float* __restrict__ Wih_c0, const float* __restrict__ Whh_c0,
                      const float* __restrict__ Wih_c1, const float* __restrict__ Whh_c1,
                      const float* __restrict__ Wih_o,
                      float* wt_p0, float* wt_p1, float* wt_c0, float* wt_c1,
                      float* wt_o1, float* wt_o2, int* flags) {
  const int NW = 458752 + 524288 + 131072 + 131072 + 131072 + 98304;
  const int NF = 2 * T_ * 16 * 32;
  const int NTOT = NW + NF;
  const int gsz = gridDim.x * blockDim.x;
  for (int i = blockIdx.x * blockDim.x + threadIdx.x; i < NTOT; i += gsz) {
    int idx = i;
    if (idx < 458752) { int k = idx >> 10, c = idx & 1023;
      int wg = c >> 6, r6 = c & 63, gate = r6 >> 4, jl = r6 & 15;
      int col = gate * 256 + wg * 16 + jl;
      wt_p0[idx] = (k < 192) ? Wih_p0[col * 192 + k] : Whh_p0[col * 256 + (k - 192)]; continue; }
    idx -= 458752;
    if (idx < 524288) { int k = idx >> 10, c = idx & 1023;
      int wg = c >> 6, r6 = c & 63, gate = r6 >> 4, jl = r6 & 15;
      int col = gate * 256 + wg * 16 + jl;
      wt_p1[idx] = (k < 256) ? Wih_p1[col * 256 + k] : Whh_p1[col * 256 + (k - 256)]; continue; }
    idx -= 524288;
    if (idx < 131072) { int k = idx >> 9, r = idx & 511;
      wt_c0[idx] = (k < 128) ? Wih_c0[r * 128 + k] : Whh_c0[r * 128 + (k - 128)]; continue; }
    idx -= 131072;
    if (idx < 131072) { int k = idx >> 9, r = idx & 511;
      wt_c1[idx] = (k < 128) ? Wih_c1[r * 128 + k] : Whh_c1[r * 128 + (k - 128)]; continue; }
    idx -= 131072;
    if (idx < 131072) { int k = idx >> 9, r = idx & 511;
      wt_o1[idx] = Wih_o[r * 448 + k]; continue; }
    idx -= 131072;
    if (idx < 98304) { int k = idx >> 9, r = idx & 511;
      wt_o2[idx] = Wih_o[r * 448 + 256 + k]; continue; }
    idx -= 98304;
    flags[idx] = 0;
  }
}

// ---------------------------------------------------------------------------
// opre2K: parallel over t. opre2[t][e][512] = Wih_o[:,256:448] @ x(t,e)  (bf16)
// ---------------------------------------------------------------------------
__global__ void opre2K(const float* __restrict__ feat, const float* __restrict__ wt_o2,
                       __hip_bfloat16* __restrict__ opre2) {
  __shared__ float xb[192 * 8];
  const int t = blockIdx.x, tid = threadIdx.x;
  const float* ft = feat + (size_t)t * 640;
  for (int idx = tid; idx < 192 * 8; idx += 256) {
    int k = idx >> 3, e = idx & 7;
    xb[idx] = (k < 128) ? ft[k] : ft[128 + e * 64 + (k - 128)];
  }
  __syncthreads();
  const int r = tid;
  float A0[8] = {0,0,0,0,0,0,0,0};
  float A1[8] = {0,0,0,0,0,0,0,0};
  const float4* x4 = (const float4*)xb;
  #pragma unroll 2
  for (int k = 0; k < 192; ++k) {
    float w0 = wt_o2[k * 512 + r];
    float w1 = wt_o2[k * 512 + 256 + r];
    float4 a = x4[k * 2], b = x4[k * 2 + 1];
    FMA_8(A0, w0, a, b);
    FMA_8(A1, w1, a, b);
  }
  #pragma unroll
  for (int e = 0; e < 8; ++e) {
    opre2[((size_t)t * 8 + e) * 512 + r]       = __float2bfloat16(A0[e]);
    opre2[((size_t)t * 8 + e) * 512 + 256 + r] = __float2bfloat16(A1[e]);
  }
}

// ---------------------------------------------------------------------------
// phaseA: 32 WGs. WG 0-15 = G1 (layer0), WG 16-31 = G2 (layer1, trailing).
// NEW (r7): weights live in LDS (loaded once): G1 448x64 = 114.7 KB,
// G2 512x64 = 131 KB; + exchange buffers => 155.6 KB <= 160 KB/CU, 1 WG/CU.
// Hot loop is pure VALU + LDS (weight ds_read_b32, 2-way aliasing = free;
// x reads are wave-uniform b128 broadcasts). Barriers now drain only the
// tiny exchange traffic, not a weight stream. Sync protocol = r6 flag lines.
// ---------------------------------------------------------------------------
__launch_bounds__(256, 1)
__global__ void phaseA(const float* __restrict__ feat,
                       const float* __restrict__ pre_h0, const float* __restrict__ pre_c0,
                       const float* __restrict__ wt_p0, const float* __restrict__ wt_p1,
                       const float* __restrict__ b_p0, const float* __restrict__ b_p1,
                       float* __restrict__ h0all, float* __restrict__ h1all,
                       int* __restrict__ flagsA, int* __restrict__ flagsB) {
  __shared__ float lds[38912];   // 155,648 B
  const int wg = blockIdx.x, tid = threadIdx.x;
  const int r6 = tid & 63, kq = tid >> 6;
  const int uj = tid >> 3, ue = tid & 7;

  if (wg < 16) {
    // ============================ G1: layer0 ============================
    float* wl   = lds;            // 28672: weights [k][64], k<448
    float* xbuf = lds + 28672;    // 1536: x(t) [k][e]
    float* hsf  = lds + 30208;    // 2048: h0(t-1) [k][e]
    float* gl   = lds + 32256;    // 2048: partials
    for (int idx = tid; idx < 28672; idx += 256)
      wl[idx] = wt_p0[(size_t)(idx >> 6) * 1024 + wg * 64 + (idx & 63)];
    const int j = wg * 16 + uj;
    float creg = 0.f, bi = 0.f, bff = 0.f, bg = 0.f, bo = 0.f;
    if (tid < 128) {
      creg = pre_c0[(ue * 2 + 0) * 256 + j];
      bi = b_p0[j]; bff = b_p0[256 + j]; bg = b_p0[512 + j]; bo = b_p0[768 + j];
    }
    for (int idx = tid; idx < 2048; idx += 256) {
      int k = idx >> 3, e = idx & 7;
      hsf[idx] = pre_h0[(e * 2 + 0) * 256 + k];
    }
    for (int idx = tid; idx < 1536; idx += 256) {
      int k = idx >> 3, e = idx & 7;
      xbuf[idx] = (k < 128) ? feat[k] : feat[128 + e * 64 + (k - 128)];
    }
    __syncthreads();
    float Ax[8] = {0,0,0,0,0,0,0,0};
    {
      const float4* x4 = (const float4*)xbuf;
      #pragma unroll 8
      for (int k = kq * 48; k < kq * 48 + 48; ++k) {
        float w = wl[k * 64 + r6];
        float4 a = x4[k * 2], b = x4[k * 2 + 1];
        FMA_8(Ax, w, a, b);
      }
    }
    for (int t = 0; t < T_; ++t) {
      float px[6];
      if (t + 1 < T_) {
        const float* ft1 = feat + (size_t)(t + 1) * 640;
        #pragma unroll
        for (int i = 0; i < 6; ++i) {
          int idx = tid + i * 256; int k = idx >> 3, e = idx & 7;
          px[i] = (k < 128) ? ft1[k] : ft1[128 + e * 64 + (k - 128)];
        }
      }
      float A[8];
      #pragma unroll
      for (int i = 0; i < 8; ++i) A[i] = Ax[i];
      {  // h-part: k in [192+kq*64, +64), weights from LDS
        const float4* h4 = (const float4*)hsf;
        const int kb = 192 + kq * 64;
        #pragma unroll 8
        for (int k = kb; k < kb + 64; ++k) {
          float w = wl[k * 64 + r6];
          int kk = k - 192;
          float4 a = h4[kk * 2], b = h4[kk * 2 + 1];
          FMA_8(A, w, a, b);
        }
      }
      {
        float4* g4 = (float4*)gl;
        g4[(kq * 64 + r6) * 2]     = make_float4(A[0], A[1], A[2], A[3]);
        g4[(kq * 64 + r6) * 2 + 1] = make_float4(A[4], A[5], A[6], A[7]);
      }
      __syncthreads();                             // S1: gl ready
      if (tid < 128) {
        float s0 = 0.f, s1 = 0.f, s2 = 0.f, s3 = 0.f;
        #pragma unroll
        for (int q = 0; q < 4; ++q) {
          s0 += gl[q * 512 + tid];       s1 += gl[q * 512 + 128 + tid];
          s2 += gl[q * 512 + 256 + tid]; s3 += gl[q * 512 + 384 + tid];
        }
        float c2 = sigm(s1 + bff) * creg + sigm(s0 + bi) * tanh_(s2 + bg);
        float h2 = sigm(s3 + bo) * tanh_(c2);
        creg = c2;
        __hip_atomic_store(&h0all[(size_t)t * 2048 + wg * 128 + tid], h2,
                           __ATOMIC_RELAXED, __HIP_MEMORY_SCOPE_AGENT);
      }
      __syncthreads();                             // S2: publish drained (vmcnt0)
      if (tid == 0)
        __hip_atomic_store(&flagsA[((size_t)t * 16 + wg) * 32], 1,
                           __ATOMIC_RELAXED, __HIP_MEMORY_SCOPE_AGENT);
      if (t + 1 >= T_) break;
      #pragma unroll
      for (int i = 0; i < 6; ++i) xbuf[tid + i * 256] = px[i];
      __syncthreads();                             // S3: xbuf = x(t+1)
      #pragma unroll
      for (int i = 0; i < 8; ++i) Ax[i] = 0.f;
      {  // x-part of t+1 in the sync shadow
        const float4* x4 = (const float4*)xbuf;
        #pragma unroll 8
        for (int k = kq * 48; k < kq * 48 + 48; ++k) {
          float w = wl[k * 64 + r6];
          float4 a = x4[k * 2], b = x4[k * 2 + 1];
          FMA_8(Ax, w, a, b);
        }
      }
      if (tid < 16) {                              // parallel 16-line detect
        const int* fp = flagsA + ((size_t)t * 16 + tid) * 32;
        while (aload32(fp) == 0) __builtin_amdgcn_s_sleep(1);
      }
      __syncthreads();                             // S4: all 16 published
      {
        const ull* s8 = (const ull*)(h0all + (size_t)t * 2048);
        ull* d8 = (ull*)hsf;
        #pragma unroll
        for (int i = 0; i < 4; ++i) d8[tid * 4 + i] = aload64(s8 + tid * 4 + i);
      }
      __syncthreads();                             // S5: hsf = h0(t)
    }
  } else {
    // ============================ G2: layer1 ============================
    const int wgl = wg - 16;
    float* wl  = lds;             // 32768: weights [k][64], k<512
    float* xh0 = lds + 32768;     // 2048: h0(t) [k][e]
    float* hsf = lds + 34816;     // 2048: h1(t-1) [k][e]
    float* gl  = lds + 36864;     // 2048
    for (int idx = tid; idx < 32768; idx += 256)
      wl[idx] = wt_p1[(size_t)(idx >> 6) * 1024 + wgl * 64 + (idx & 63)];
    const int j = wgl * 16 + uj;
    float creg = 0.f, bi = 0.f, bff = 0.f, bg = 0.f, bo = 0.f;
    if (tid < 128) {
      creg = pre_c0[(ue * 2 + 1) * 256 + j];
      bi = b_p1[j]; bff = b_p1[256 + j]; bg = b_p1[512 + j]; bo = b_p1[768 + j];
    }
    for (int idx = tid; idx < 2048; idx += 256) {
      int k = idx >> 3, e = idx & 7;
      hsf[idx] = pre_h0[(e * 2 + 1) * 256 + k];
    }
    __syncthreads();
    if (tid < 16) {
      const int* fp = flagsA + (size_t)tid * 32;   // step 0 flags
      while (aload32(fp) == 0) __builtin_amdgcn_s_sleep(1);
    }
    __syncthreads();
    {
      const ull* s8 = (const ull*)h0all;
      ull* d8 = (ull*)xh0;
      #pragma unroll
      for (int i = 0; i < 4; ++i) d8[tid * 4 + i] = aload64(s8 + tid * 4 + i);
    }
    __syncthreads();
    float Ax[8] = {0,0,0,0,0,0,0,0};
    {
      const float4* x4 = (const float4*)xh0;
      #pragma unroll 8
      for (int k = kq * 64; k < kq * 64 + 64; ++k) {
        float w = wl[k * 64 + r6];
        float4 a = x4[k * 2], b = x4[k * 2 + 1];
        FMA_8(Ax, w, a, b);
      }
    }
    for (int t = 0; t < T_; ++t) {
      float A[8];
      #pragma unroll
      for (int i = 0; i < 8; ++i) A[i] = Ax[i];
      {  // h-part: k in [256+kq*64, +64), weights from LDS
        const float4* h4 = (const float4*)hsf;
        const int kb = 256 + kq * 64;
        #pragma unroll 8
        for (int k = kb; k < kb + 64; ++k) {
          float w = wl[k * 64 + r6];
          int kk = k - 256;
          float4 a = h4[kk * 2], b = h4[kk * 2 + 1];
          FMA_8(A, w, a, b);
        }
      }
      {
        float4* g4 = (float4*)gl;
        g4[(kq * 64 + r6) * 2]     = make_float4(A[0], A[1], A[2], A[3]);
        g4[(kq * 64 + r6) * 2 + 1] = make_float4(A[4], A[5], A[6], A[7]);
      }
      __syncthreads();                             // S1
      if (tid < 128) {
        float s0 = 0.f, s1 = 0.f, s2 = 0.f, s3 = 0.f;
        #pragma unroll
        for (int q = 0; q < 4; ++q) {
          s0 += gl[q * 512 + tid];       s1 += gl[q * 512 + 128 + tid];
          s2 += gl[q * 512 + 256 + tid]; s3 += gl[q * 512 + 384 + tid];
        }
        float c2 = sigm(s1 + bff) * creg + sigm(s0 + bi) * tanh_(s2 + bg);
        float h2 = sigm(s3 + bo) * tanh_(c2);
        creg = c2;
        __hip_atomic_store(&h1all[(size_t)t * 2048 + wgl * 128 + tid], h2,
                           __ATOMIC_RELAXED, __HIP_MEMORY_SCOPE_AGENT);
      }
      __syncthreads();                             // S2: publish drained
      if (tid == 0)
        __hip_atomic_store(&flagsB[((size_t)t * 16 + wgl) * 32], 1,
                           __ATOMIC_RELAXED, __HIP_MEMORY_SCOPE_AGENT);
      if (t + 1 >= T_) break;
      if (tid < 32) {                              // combined detect
        const int* fp = (tid < 16)
            ? flagsA + ((size_t)(t + 1) * 16 + tid) * 32
            : flagsB + ((size_t)t * 16 + (tid - 16)) * 32;
        while (aload32(fp) == 0) __builtin_amdgcn_s_sleep(1);
      }
      __syncthreads();                             // S3: both ready
      {                                            // both gathers back-to-back
        const ull* s0p = (const ull*)(h0all + (size_t)(t + 1) * 2048);
        const ull* s1p = (const ull*)(h1all + (size_t)t * 2048);
        ull v0[4], v1[4];
        #pragma unroll
        for (int i = 0; i < 4; ++i) v0[i] = aload64(s0p + tid * 4 + i);
        #pragma unroll
        for (int i = 0; i < 4; ++i) v1[i] = aload64(s1p + tid * 4 + i);
        ull* d0 = (ull*)xh0; ull* d1 = (ull*)hsf;
        #pragma unroll
        for (int i = 0; i < 4; ++i) { d0[tid * 4 + i] = v0[i]; d1[tid * 4 + i] = v1[i]; }
      }
      __syncthreads();                             // S4: xh0=h0(t+1), hsf=h1(t)
      #pragma unroll
      for (int i = 0; i < 8; ++i) Ax[i] = 0.f;
      {  // h0-part of t+1
        const float4* x4 = (const float4*)xh0;
        #pragma unroll 8
        for (int k = kq * 64; k < kq * 64 + 64; ++k) {
          float w = wl[k * 64 + r6];
          float4 a = x4[k * 2], b = x4[k * 2 + 1];
          FMA_8(Ax, w, a, b);
        }
      }
    }
  }
}

// ---------------------------------------------------------------------------
// fcK: parallel over t. pre_out[t][e][c] = leaky(Wfc @ h1all[t] + bfc)
// ---------------------------------------------------------------------------
__global__ void fcK(const float* __restrict__ h1all, const float* __restrict__ Wfc,
                    const float* __restrict__ bfc, float* __restrict__ pre_out) {
  __shared__ float hl[2048];
  const int t = blockIdx.x, tid = threadIdx.x;
  for (int idx = tid; idx < 2048; idx += 256) hl[idx] = h1all[(size_t)t * 2048 + idx];
  __syncthreads();
  const int c = tid >> 1, half = tid & 1;
  float b = bfc[c];
  float acc[4] = {b, b, b, b};
  const float4* h4 = (const float4*)hl;
  const float* wrow = Wfc + c * 256;
  #pragma unroll 4
  for (int k = 0; k < 256; ++k) {
    float w = wrow[k];
    float4 x = h4[k * 2 + half];
    acc[0] = fmaf(w, x.x, acc[0]); acc[1] = fmaf(w, x.y, acc[1]);
    acc[2] = fmaf(w, x.z, acc[2]); acc[3] = fmaf(w, x.w, acc[3]);
  }
  #pragma unroll
  for (int i = 0; i < 4; ++i) {
    int e = half * 4 + i;
    float v = acc[i];
    v = (v > 0.f) ? v : 0.05f * v;
    pre_out[((size_t)t * 8 + e) * 128 + c] = v;
  }
}

// ---------------------------------------------------------------------------
// comm cell for phase B
// ---------------------------------------------------------------------------
__device__ __forceinline__ void comm_cell(
    const float* __restrict__ wt, const float* __restrict__ bias,
    const float* xin, float* hL, float* cL, float* glb, float* hout,
    float alpha, int tid) {
  const int r = tid;
  float A0[8] = {0,0,0,0,0,0,0,0};
  float A1[8] = {0,0,0,0,0,0,0,0};
  const float4* x4 = (const float4*)xin;
  #pragma unroll 2
  for (int k = 0; k < 128; ++k) {
    float w0 = wt[k * 512 + r];
    float w1 = wt[k * 512 + 256 + r];
    float4 a = x4[k * 2], b = x4[k * 2 + 1];
    FMA_8(A0, w0, a, b);
    FMA_8(A1, w1, a, b);
  }
  const float4* h4 = (const float4*)hL;
  #pragma unroll 2
  for (int k = 0; k < 128; ++k) {
    float w0 = wt[(128 + k) * 512 + r];
    float w1 = wt[(128 + k) * 512 + 256 + r];
    float4 a = h4[k * 2], b = h4[k * 2 + 1];
    FMA_8(A0, w0, a, b);
    FMA_8(A1, w1, a, b);
  }
  {
    float4* g4 = (float4*)glb;
    g4[r * 2]             = make_float4(A0[0], A0[1], A0[2], A0[3]);
    g4[r * 2 + 1]         = make_float4(A0[4], A0[5], A0[6], A0[7]);
    g4[(256 + r) * 2]     = make_float4(A1[0], A1[1], A1[2], A1[3]);
    g4[(256 + r) * 2 + 1] = make_float4(A1[4], A1[5], A1[6], A1[7]);
  }
  __syncthreads();
  for (int idx = tid; idx < 1024; idx += 256) {
    int jj = idx >> 3, tt = idx & 7;
    float gi = glb[jj * 8 + tt]         + bias[jj];
    float gf = glb[(128 + jj) * 8 + tt] + bias[128 + jj];
    float gg = glb[(256 + jj) * 8 + tt] + bias[256 + jj];
    float go = glb[(384 + jj) * 8 + tt] + bias[384 + jj];
    float cold = cL[idx], hold = hL[idx];
    float c2 = sigm(gf) * cold + sigm(gi) * tanh_(gg);
    float h2 = sigm(go) * tanh_(c2);
    float hb = fmaf(alpha, h2 - hold, hold);
    float cb = fmaf(alpha, c2 - cold, cold);
    hL[idx] = hb; cL[idx] = cb;
    if (hout) hout[idx] = hb;
  }
  __syncthreads();
}

// ---------------------------------------------------------------------------
// phaseB: parallel over t (8 timesteps / WG); emits opre1 (incl. b_o)
// ---------------------------------------------------------------------------
__launch_bounds__(256, 2)
__global__ void phaseB(const float* __restrict__ pre_out,
                       const float* __restrict__ wt_c0, const float* __restrict__ wt_c1,
                       const float* __restrict__ b_c0, const float* __restrict__ b_c1,
                       const float* __restrict__ wt_o1, const float* __restrict__ b_o,
                       float* __restrict__ opre1) {
  __shared__ float pol[128 * 8];
  __shared__ float ch0[128 * 8], cc0[128 * 8], ch1[128 * 8], cc1[128 * 8];
  __shared__ float h0b[128 * 8];
  __shared__ float glb[512 * 8];
  const int wg = blockIdx.x, tid = threadIdx.x;
  const int t0 = wg * 8;
  for (int idx = tid; idx < 1024; idx += 256) { ch0[idx]=0.f; cc0[idx]=0.f; ch1[idx]=0.f; cc1[idx]=0.f; }
  __syncthreads();
  float alpha = 1.0f;
  for (int rd = 0; rd < 3; ++rd) {
    for (int e = 0; e < E_; ++e) {
      for (int idx = tid; idx < 1024; idx += 256) {
        int tt = idx >> 7, k = idx & 127;
        pol[k * 8 + tt] = pre_out[(((size_t)(t0 + tt)) * 8 + e) * 128 + k];
      }
      __syncthreads();
      comm_cell(wt_c0, b_c0, pol, ch0, cc0, glb, h0b, alpha, tid);
      comm_cell(wt_c1, b_c1, h0b, ch1, cc1, glb, nullptr, alpha, tid);
    }
    alpha *= 0.333f;
  }
  {
    const int r = tid;
    float A0[8], A1[8];
    #pragma unroll
    for (int tt = 0; tt < 8; ++tt) { A0[tt] = b_o[r]; A1[tt] = b_o[256 + r]; }
    const float4* c04 = (const float4*)cc0;
    const float4* c14 = (const float4*)cc1;
    #pragma unroll 2
    for (int k = 0; k < 128; ++k) {
      float w0 = wt_o1[k * 512 + r], w1 = wt_o1[k * 512 + 256 + r];
      float4 a = c04[k * 2], b = c04[k * 2 + 1];
      FMA_8(A0, w0, a, b);
      FMA_8(A1, w1, a, b);
    }
    #pragma unroll 2
    for (int k = 0; k < 128; ++k) {
      float w0 = wt_o1[(128 + k) * 512 + r], w1 = wt_o1[(128 + k) * 512 + 256 + r];
      float4 a = c14[k * 2], b = c14[k * 2 + 1];
      FMA_8(A0, w0, a, b);
      FMA_8(A1, w1, a, b);
    }
    #pragma unroll
    for (int tt = 0; tt < 8; ++tt) {
      opre1[((size_t)(t0 + tt)) * 512 + r]       = A0[tt];
      opre1[((size_t)(t0 + tt)) * 512 + 256 + r] = A1[tt];
    }
  }
}

// ---------------------------------------------------------------------------
// phaseC: 8 WGs, one per ensemble e. No inter-WG sync; Whh_o in registers.
// ---------------------------------------------------------------------------
__launch_bounds__(256, 1)
__global__ void phaseC(const float* __restrict__ opre1, const __hip_bfloat16* __restrict__ opre2,
                       const float* __restrict__ Whh_o, const float* __restrict__ out_h0,
                       const float* __restrict__ out_c0, float* __restrict__ oh_g) {
  __shared__ float ohl[128];
  __shared__ float gl[512];
  const int e = blockIdx.x, tid = threadIdx.x;
  const int r0 = tid, r1 = tid + 256;
  float w0[128], w1[128];
  #pragma unroll
  for (int k = 0; k < 128; ++k) w0[k] = Whh_o[r0 * 128 + k];
  #pragma unroll
  for (int k = 0; k < 128; ++k) w1[k] = Whh_o[r1 * 128 + k];
  if (tid < 128) ohl[tid] = out_h0[e * 128 + tid];
  float creg = (tid < 128) ? out_c0[e * 128 + tid] : 0.f;
  __syncthreads();
  float p0a = opre1[r0], p0b = opre1[r1];
  float q0a = __bfloat162float(opre2[(size_t)e * 512 + r0]);
  float q0b = __bfloat162float(opre2[(size_t)e * 512 + r1]);
  for (int t = 0; t < T_; ++t) {
    float a0 = p0a + q0a, a1 = p0b + q0b;
    if (t + 1 < T_) {
      p0a = opre1[(size_t)(t + 1) * 512 + r0];
      p0b = opre1[(size_t)(t + 1) * 512 + r1];
      q0a = __bfloat162float(opre2[((size_t)(t + 1) * 8 + e) * 512 + r0]);
      q0b = __bfloat162float(opre2[((size_t)(t + 1) * 8 + e) * 512 + r1]);
    }
    const float4* o4 = (const float4*)ohl;
    #pragma unroll
    for (int kk = 0; kk < 32; ++kk) {
      float4 x = o4[kk];
      a0 = fmaf(w0[kk * 4 + 0], x.x, a0); a0 = fmaf(w0[kk * 4 + 1], x.y, a0);
      a0 = fmaf(w0[kk * 4 + 2], x.z, a0); a0 = fmaf(w0[kk * 4 + 3], x.w, a0);
      a1 = fmaf(w1[kk * 4 + 0], x.x, a1); a1 = fmaf(w1[kk * 4 + 1], x.y, a1);
      a1 = fmaf(w1[kk * 4 + 2], x.z, a1); a1 = fmaf(w1[kk * 4 + 3], x.w, a1);
    }
    gl[r0] = a0; gl[r1] = a1;
    __syncthreads();
    if (tid < 128) {
      float gi = gl[tid], gf = gl[128 + tid], gg = gl[256 + tid], go = gl[384 + tid];
      float c2 = sigm(gf) * creg + sigm(gi) * tanh_(gg);
      float h2 = sigm(go) * tanh_(c2);
      creg = c2;
      ohl[tid] = h2;
      oh_g[(size_t)t * 1024 + e * 128 + tid] = h2;
    }
    __syncthreads();
  }
}

// ---------------------------------------------------------------------------
// phaseD: parallel over t: softmaxes
// ---------------------------------------------------------------------------
__global__ void phaseD(const float* __restrict__ oh_g,
                       const float* __restrict__ Wtar, const float* __restrict__ btar,
                       const float* __restrict__ Wdir, const float* __restrict__ bdir,
                       float* __restrict__ outp) {
  __shared__ float ohl[1024];
  const int t = blockIdx.x, tid = threadIdx.x;  // 64 threads
  for (int idx = tid; idx < 1024; idx += 64) ohl[idx] = oh_g[(size_t)t * 1024 + idx];
  __syncthreads();
  const int f = tid;
  for (int e = 0; e < E_; ++e) {
    float acc = btar[f];
    const float* wr = Wtar + f * 128;
    #pragma unroll 4
    for (int k = 0; k < 128; ++k) acc = fmaf(wr[k], ohl[e * 128 + k], acc);
    float m = acc;
    #pragma unroll
    for (int off = 32; off; off >>= 1) m = fmaxf(m, __shfl_xor(m, off, 64));
    float ex = __expf(acc - m);
    float s = ex;
    #pragma unroll
    for (int off = 32; off; off >>= 1) s += __shfl_xor(s, off, 64);
    outp[((size_t)t * 8 + e) * 64 + f] = ex / s;
  }
  if (tid < 8) {
    int e = tid;
    float d0 = bdir[0], d1 = bdir[1], d2 = bdir[2];
    #pragma unroll 4
    for (int k = 0; k < 128; ++k) {
      float x = ohl[e * 128 + k];
      d0 = fmaf(Wdir[k], x, d0);
      d1 = fmaf(Wdir[128 + k], x, d1);
      d2 = fmaf(Wdir[256 + k], x, d2);
    }
    float m = fmaxf(d0, fmaxf(d1, d2));
    float x0 = __expf(d0 - m), x1 = __expf(d1 - m), x2 = __expf(d2 - m);
    float s = x0 + x1 + x2;
    float* dp = outp + (size_t)T_ * 8 * 64 + ((size_t)t * 8 + e) * 3;
    dp[0] = x0 / s; dp[1] = x1 / s; dp[2] = x2 / s;
  }
}

extern "C" void kernel_launch(void* const* d_in, const int* in_sizes, int n_in,
                              void* d_out, int out_size, void* d_ws, size_t ws_size,
                              hipStream_t stream) {
  (void)in_sizes; (void)n_in; (void)out_size; (void)ws_size;
  const float* feat   = (const float*)d_in[0];
  const float* pre_h0 = (const float*)d_in[1];
  const float* pre_c0 = (const float*)d_in[2];
  const float* out_h0 = (const float*)d_in[3];
  const float* out_c0 = (const float*)d_in[4];
  const float* Wih_p0 = (const float*)d_in[5];
  const float* Whh_p0 = (const float*)d_in[6];
  const float* b_p0   = (const float*)d_in[7];
  const float* Wih_p1 = (const float*)d_in[8];
  const float* Whh_p1 = (const float*)d_in[9];
  const float* b_p1   = (const float*)d_in[10];
  const float* Wfc    = (const float*)d_in[11];
  const float* bfc    = (const float*)d_in[12];
  const float* Wih_c0 = (const float*)d_in[13];
  const float* Whh_c0 = (const float*)d_in[14];
  const float* b_c0   = (const float*)d_in[15];
  const float* Wih_c1 = (const float*)d_in[16];
  const float* Whh_c1 = (const float*)d_in[17];
  const float* b_c1   = (const float*)d_in[18];
  const float* Wih_o  = (const float*)d_in[19];
  const float* Whh_o  = (const float*)d_in[20];
  const float* b_o    = (const float*)d_in[21];
  const float* Wtar   = (const float*)d_in[22];
  const float* btar   = (const float*)d_in[23];
  const float* Wdir   = (const float*)d_in[24];
  const float* bdir   = (const float*)d_in[25];
  float* outp = (float*)d_out;

  float* ws = (float*)d_ws;
  size_t off = 0;
  float* pre_outB = ws + off; off += (size_t)T_ * E_ * 128;
  float* opre1    = ws + off; off += (size_t)T_ * 512;
  float* oh_g     = ws + off; off += (size_t)T_ * E_ * 128;
  float* wt_p0    = ws + off; off += (size_t)448 * 1024;
  float* wt_p1    = ws + off; off += (size_t)512 * 1024;
  float* wt_c0    = ws + off; off += (size_t)256 * 512;
  float* wt_c1    = ws + off; off += (size_t)256 * 512;
  float* wt_o1    = ws + off; off += (size_t)256 * 512;
  float* wt_o2    = ws + off; off += (size_t)192 * 512;
  __hip_bfloat16* opre2 = (__hip_bfloat16*)(ws + off);
  off += (size_t)T_ * E_ * 512 / 2;
  float* h0all = ws + off; off += (size_t)T_ * 2048;
  float* h1all = ws + off; off += (size_t)T_ * 2048;
  int* flags   = (int*)(ws + off);              // 2 * T * 16 * 32 ints (16 MB)
  int* flagsA  = flags;
  int* flagsB  = flags + (size_t)T_ * 16 * 32;

  initK<<<dim3(1024), dim3(256), 0, stream>>>(
      Wih_p0, Whh_p0, Wih_p1, Whh_p1, Wih_c0, Whh_c0, Wih_c1, Whh_c1, Wih_o,
      wt_p0, wt_p1, wt_c0, wt_c1, wt_o1, wt_o2, flags);
  opre2K<<<dim3(T_), dim3(256), 0, stream>>>(feat, wt_o2, opre2);
  phaseA<<<dim3(32), dim3(256), 0, stream>>>(
      feat, pre_h0, pre_c0, wt_p0, wt_p1, b_p0, b_p1, h0all, h1all, flagsA, flagsB);
  fcK<<<dim3(T_), dim3(256), 0, stream>>>(h1all, Wfc, bfc, pre_outB);
  phaseB<<<dim3(T_ / 8), dim3(256), 0, stream>>>(
      pre_outB, wt_c0, wt_c1, b_c0, b_c1, wt_o1, b_o, opre1);
  phaseC<<<dim3(E_), dim3(256), 0, stream>>>(
      opre1, opre2, Whh_o, out_h0, out_c0, oh_g);
  phaseD<<<dim3(T_), dim3(64), 0, stream>>>(oh_g, Wtar, btar, Wdir, bdir, outp);
}